// Round 8
// baseline (248.314 us; speedup 1.0000x reference)
//
#include <hip/hip_runtime.h>
#include <math.h>

#define N 8192
#define H 128
#define NEV 64
#define SS 20
#define MAXD 512
#define MAXDIRTY 128
#define RPB 32

__device__ __forceinline__ unsigned rne16(float f) {          // f32 -> bf16 bits (RNE)
    unsigned x = __float_as_uint(f);
    return (x + 0x7fffu + ((x >> 16) & 1u)) >> 16;
}
__device__ __forceinline__ float bf2f(unsigned short h) {     // bf16 bits -> f32
    return __uint_as_float(((unsigned)h) << 16);
}

// ---------------------------------------------------------------------------
// k_init: as round 6 + zeroes hneeds[128] (per-SLOT h-refresh flags).
// ---------------------------------------------------------------------------
__global__ __launch_bounds__(256) void k_init(
    const int* __restrict__ u, const int* __restrict__ v,
    const float* __restrict__ t, const float* __restrict__ lastt,
    int* __restrict__ fu, int* __restrict__ zsrc, int* __restrict__ wslot,
    float* __restrict__ dtv, int* __restrict__ deg, int* __restrict__ dcnt,
    int* __restrict__ needh, int* __restrict__ hneeds)
{
    __shared__ int fuL[N];   // 32 KB
    const int tid = threadIdx.x;
    for (int i = tid; i < N; i += 256) fuL[i] = 0x7FFFFFFF;
    if (tid < 128) { deg[tid] = 0; dcnt[tid] = 0; hneeds[tid] = 0; }
    if (tid < NEV) needh[tid] = 0;
    __syncthreads();
    if (tid < 2 * NEV) {
        const int e = tid >> 1, i = tid & 1;
        const int node = i ? u[e] : v[e];       // i=0 -> row v, i=1 -> row u
        atomicMin(&fuL[node], tid);
    }
    __syncthreads();
    for (int i = tid; i < N; i += 256) fu[i] = fuL[i];
    if (tid < 2 * NEV) {
        const int e = tid >> 1, i = tid & 1;
        const int node = i ? u[e] : v[e];
        const int f = fuL[node];
        wslot[tid] = f;
        zsrc[tid] = (f < 2 * e) ? f : -1;
        const int dtn = i ? v[e] : u[e];        // crossed dt
        int pt = -1;
        for (int e2 = e - 1; e2 >= 0; --e2)
            if (u[e2] == dtn || v[e2] == dtn) { pt = e2; break; }
        const float lv = (pt >= 0) ? t[pt] : lastt[dtn];
        dtv[tid] = t[e] - lv;
    }
}

// ---------------------------------------------------------------------------
// k_emb: h_tab = emb @ W_h.T + b_h ; z_out = emb copy ; d0/d1 rate dots.
// [byte-identical to round 6]
// ---------------------------------------------------------------------------
__global__ __launch_bounds__(512) void k_emb(
    const float* __restrict__ emb, const float* __restrict__ W_h,
    const float* __restrict__ b_h, const float* __restrict__ W_om,
    float* __restrict__ h_tab, float* __restrict__ z_out,
    float* __restrict__ d0, float* __restrict__ d1)
{
    const int tid = threadIdx.x;
    const int c = tid & 127;
    const int s = tid >> 7;             // 0..3
    const int r0 = blockIdx.x * RPB;

    __shared__ __align__(16) float z4[4 * 128];
    __shared__ float pr[8 * 128];

    float whr[32];
#pragma unroll
    for (int i = 0; i < 32; ++i) whr[i] = W_h[c * H + s * 32 + i];
    const float bh_c = b_h[c];

    const int lane = tid & 63;
    const int wid = tid >> 6;
    const int kof = (wid >= 4) ? 256 : 0;
    const float wk_l = W_om[kof + lane]      + W_om[kof + 128 + lane];
    const float wk_h = W_om[kof + 64 + lane] + W_om[kof + 192 + lane];

    for (int b = 0; b < RPB / 4; ++b) {
        const int rbase = r0 + b * 4;
        __syncthreads();
        const float zv = emb[(size_t)rbase * H + tid];
        z4[tid] = zv;
        z_out[(size_t)rbase * H + tid] = zv;
        __syncthreads();

#pragma unroll
        for (int rr = 0; rr < 4; ++rr) {
            float a = 0.f;
#pragma unroll
            for (int i4 = 0; i4 < 8; ++i4) {
                const float4 zz = *(const float4*)&z4[rr * 128 + s * 32 + i4 * 4];
                a += zz.x * whr[i4 * 4] + zz.y * whr[i4 * 4 + 1] +
                     zz.z * whr[i4 * 4 + 2] + zz.w * whr[i4 * 4 + 3];
            }
            pr[(s * 4 + rr) * 128 + c] = a;
        }
        {
            const int rr = wid & 3;
            float val = z4[rr * 128 + lane] * wk_l + z4[rr * 128 + 64 + lane] * wk_h;
#pragma unroll
            for (int off = 32; off > 0; off >>= 1) val += __shfl_xor(val, off);
            if (lane == 0) {
                if (wid < 4) d0[rbase + rr] = val;
                else         d1[rbase + rr] = val;
            }
        }
        __syncthreads();
        {
            const int rr = s;
            const float h = pr[(0 * 4 + rr) * 128 + c] + pr[(1 * 4 + rr) * 128 + c] +
                            pr[(2 * 4 + rr) * 128 + c] + pr[(3 * 4 + rr) * 128 + c] + bh_c;
            h_tab[(size_t)(rbase + rr) * H + c] = h;
        }
    }
}

// ---------------------------------------------------------------------------
// k_nbr: compact neighbor lists.  [byte-identical to round 6]
// ---------------------------------------------------------------------------
__global__ __launch_bounds__(256) void k_nbr(
    const int* __restrict__ u, const int* __restrict__ v,
    const float* __restrict__ A, const float* __restrict__ S,
    int* __restrict__ deg, float* __restrict__ sumv,
    int* __restrict__ nbr_i, float* __restrict__ nbr_e)
{
    const int slot = blockIdx.x;
    const int e = slot >> 1, side = slot & 1;
    const int row = (side == 0) ? v[e] : u[e];
    const size_t base = (size_t)row * N;
    const int tid = threadIdx.x;
    float lsum = 0.f;
    for (int j = tid; j < N; j += 256) {
        if (A[base + j] > 0.f) {
            const float ev = expf(S[base + j]);
            lsum += ev;
            const int p = atomicAdd(&deg[slot], 1);
            if (p < MAXD) {
                nbr_i[slot * MAXD + p] = j;
                nbr_e[slot * MAXD + p] = ev;
            }
        }
    }
    __shared__ float rs[256];
    rs[tid] = lsum;
    __syncthreads();
    for (int off = 128; off > 0; off >>= 1) {
        if (tid < off) rs[tid] += rs[tid + off];
        __syncthreads();
    }
    if (tid == 0) sumv[slot] = rs[0];
}

// ---------------------------------------------------------------------------
// k_dm: as round 6 + per-SLOT hneeds[f]=1 (fixes the first-updater-only latent
// bug: every updater of a dirty-read node must refresh its h row).
// ---------------------------------------------------------------------------
__global__ __launch_bounds__(128) void k_dm(
    const int* __restrict__ deg, const float* __restrict__ sumv,
    const int* __restrict__ nbr_i, const float* __restrict__ nbr_e,
    const int* __restrict__ fu, const float* __restrict__ h_tab,
    float* __restrict__ Mstat, int* __restrict__ dcnt,
    int* __restrict__ dl_s, float* __restrict__ dl_q,
    int* __restrict__ needh, int* __restrict__ hneeds)
{
    const int slot = blockIdx.x;
    const int e = slot >> 1;
    const int c = threadIdx.x;
    const int d = min(deg[slot], MAXD);
    const float rinv = 1.f / (sumv[slot] + 1e-7f);
    float m = -INFINITY;
    for (int j0 = 0; j0 < d; ++j0) {
        const int j = nbr_i[slot * MAXD + j0];
        if (fu[j] >= 2 * e)
            m = fmaxf(m, nbr_e[slot * MAXD + j0] * rinv * h_tab[(size_t)j * H + c]);
    }
    Mstat[slot * H + c] = m;
    for (int j0 = c; j0 < d; j0 += 128) {
        const int j = nbr_i[slot * MAXD + j0];
        const int f = fu[j];
        if (f < 2 * e) {
            const int p = atomicAdd(&dcnt[slot], 1);
            if (p < MAXDIRTY) {
                dl_s[slot * MAXDIRTY + p] = f;
                dl_q[slot * MAXDIRTY + p] = nbr_e[slot * MAXD + j0] * rinv;
            }
            needh[f >> 1] = 1;
            hneeds[f] = 1;       // per-slot: ALL updaters of this node refresh h
        }
    }
}

// ---------------------------------------------------------------------------
// k_ls: lam (block 0) + survival (blocks 1..SS).  [byte-identical to round 6]
// ---------------------------------------------------------------------------
__global__ __launch_bounds__(64) void k_ls(
    const int* __restrict__ u, const int* __restrict__ v, const int* __restrict__ kk,
    const int* __restrict__ u_o, const int* __restrict__ v_o,
    const float* __restrict__ d0, const float* __restrict__ d1,
    const float* __restrict__ psi, const float* __restrict__ b_om,
    float* __restrict__ lamout, float* __restrict__ svout)
{
    const int b = threadIdx.x;
    if (blockIdx.x == 0) {
        if (b < NEV) {
            const int kv = kk[b];
            const float* dk = kv ? d1 : d0;
            const float g = 0.5f * (dk[u[b]] + dk[v[b]]) + b_om[kv];
            const float ps = psi[kv];
            const float x = fminf(75.f, fmaxf(-75.f, g / ps));
            lamout[b] = ps * log1pf(expf(x));
        }
    } else {
        const int s = blockIdx.x - 1;
        const float p0 = psi[0], p1 = psi[1], bo0 = b_om[0], bo1 = b_om[1];
        const int vo = v_o[b * SS + s], uo = u_o[b * SS + s];
        float g, x;
        g = 0.5f * (d0[u[b]] + d0[vo]) + bo0; x = fminf(75.f, fmaxf(-75.f, g / p0));
        const float ru0 = p0 * log1pf(expf(x));
        g = 0.5f * (d1[u[b]] + d1[vo]) + bo1; x = fminf(75.f, fmaxf(-75.f, g / p1));
        const float ru1 = p1 * log1pf(expf(x));
        g = 0.5f * (d1[v[b]] + d1[uo]) + bo1; x = fminf(75.f, fmaxf(-75.f, g / p1));
        const float rv1 = p1 * log1pf(expf(x));
        float val = 2.f * (ru0 + ru1) + rv1;
#pragma unroll
        for (int off = 32; off > 0; off >>= 1) val += __shfl_xor(val, off);
        if (b == 0) svout[s] = val / (float)SS;
    }
}

// ---------------------------------------------------------------------------
// k_seq v6: LDS-pure event loop. Startup stages W_S/W_R (bf16 pairs packed in
// u32, transposed [c'][c] -> per-lane stride-4B reads, conflict-free), Mstat
// (bf16), z-state (bf16), capped-8 dirty lists into LDS (146 KB). The 64-event
// loop touches NO global memory on the common path: 3 lgkm-only barriers per
// event. h state lives in global (rare dirty reads are same-CU L2-local; rare
// phase-C writes barrier-ordered within the block).
// ---------------------------------------------------------------------------
constexpr int KSEQ_LDS_BYTES =
    16384 * 4      /* Wpk  u32 [c'][c]               */ +
    16384 * 2      /* z16  bf16 [slot][c]            */ +
    16384 * 2      /* M16  bf16 [slot][c]            */ +
    512 * 4        /* hz   f32 [c][4]                */ +
    256 * 4        /* znw  f32 [2][128]              */ +
    1024 * 4       /* pr   f32 [8][128]              */ +
    128 * 4        /* dtv_l                          */ +
    1024 * 4       /* dl8q f32 [128][8]              */ +
    1024 * 4       /* dl8s int [128][8]              */ +
    (64 + 64 + 128 + 128 + 128 + 128) * 4 /* ints   */;   // = 149504

__global__ __launch_bounds__(512, 1) void k_seq(
    const int* __restrict__ u, const int* __restrict__ v,
    const float* __restrict__ W_S, const float* __restrict__ W_R,
    const float* __restrict__ W_t, const float* __restrict__ W_h,
    const float* __restrict__ b_h,
    const int* __restrict__ deg, const int* __restrict__ dcnt,
    const int* __restrict__ dl_s, const float* __restrict__ dl_q,
    const float* __restrict__ Mstat,
    const int* __restrict__ wslot, const float* __restrict__ dtv,
    const int* __restrict__ hneeds,
    float* __restrict__ h_upd, float* __restrict__ z_out)
{
    extern __shared__ unsigned char lds_raw[];
    unsigned*       Wpk  = (unsigned*)lds_raw;                    // [128c'][128c]
    unsigned short* z16  = (unsigned short*)(Wpk + 16384);        // [128sl][128c]
    unsigned short* M16  = (unsigned short*)(z16 + 16384);        // [128sl][128c]
    float* hz    = (float*)(M16 + 16384);       // [c][4] = {hs_v, hs_u, z_v, z_u}
    float* znw   = hz + 512;                    // [r][128]
    float* pr    = znw + 256;                   // [(s*2+r)][128]
    float* dtv_l = pr + 1024;                   // [128]
    float* dl8q  = dtv_l + 128;                 // [128][8]
    int*   dl8s  = (int*)(dl8q + 1024);         // [128][8]
    int*   ib      = dl8s + 1024;
    int* ev_u_l    = ib;                        // 64
    int* ev_v_l    = ib + 64;                   // 64
    int* wslot_l   = ib + 128;                  // 128
    int* deg_l     = ib + 256;                  // 128
    int* dcnt_l    = ib + 384;                  // 128
    int* hneeds_l  = ib + 512;                  // 128

    const int tid = threadIdx.x;
    const int c = tid & 127;
    const int s = tid >> 7;             // 0..3; wave-uniform

    const float wt_c = W_t[c];
    const float bh_c = b_h[c];

    // ---- stage scalars ----
    if (tid < 64)          { ev_u_l[tid] = u[tid]; ev_v_l[tid] = v[tid]; }
    else if (tid < 192)    { wslot_l[tid - 64] = wslot[tid - 64]; }
    else if (tid < 320)    { const int i = tid - 192; deg_l[i] = deg[i]; dcnt_l[i] = dcnt[i]; hneeds_l[i] = hneeds[i]; }
    else if (tid < 448)    { dtv_l[tid - 320] = dtv[tid - 320]; }

    // ---- stage weights (transposed, bf16-packed) + Mstat (bf16) ----
#pragma unroll 4
    for (int k2 = 0; k2 < 32; ++k2) {
        const int idx = tid + k2 * 512;          // 0..16383, coalesced
        const float ws = W_S[idx], wr = W_R[idx];
        const int cc = idx >> 7, cp = idx & 127;
        Wpk[cp * 128 + cc] = (rne16(wr) << 16) | rne16(ws);
        M16[idx] = (unsigned short)rne16(Mstat[idx]);
    }
    // ---- stage z-state: z16[sl] = z_out[node(sl)] for all slots ----
    {
        const int sl = tid >> 2, q = tid & 3;
        const int node = (sl & 1) ? u[sl >> 1] : v[sl >> 1];
#pragma unroll
        for (int j2 = 0; j2 < 32; ++j2) {
            const int col = q * 32 + j2;
            z16[sl * 128 + col] = (unsigned short)rne16(z_out[(size_t)node * H + col]);
        }
    }
    // ---- stage capped dirty lists ----
    {
        const int slot = tid >> 2, e4 = tid & 3;
        dl8s[slot * 8 + e4]     = dl_s[slot * MAXDIRTY + e4];
        dl8q[slot * 8 + e4]     = dl_q[slot * MAXDIRTY + e4];
        dl8s[slot * 8 + e4 + 4] = dl_s[slot * MAXDIRTY + e4 + 4];
        dl8q[slot * 8 + e4 + 4] = dl_q[slot * MAXDIRTY + e4 + 4];
    }
    __syncthreads();

    for (int e = 0; e < NEV; ++e) {
        const int uu = ev_u_l[e], vv = ev_v_l[e];
        const bool dup = (uu == vv);
        const int nh = hneeds_l[wslot_l[e * 2]] | hneeds_l[wslot_l[e * 2 + 1]];

        // ---- Phase A: hz = {hs_v, hs_u, z_v, z_u} (LDS only; dirty rare) ----
        if (tid < 256) {
            const int slot = e * 2 + s;          // s in {0,1} == side
            float m = bf2f(M16[slot * 128 + c]);
            const int nd = dcnt_l[slot];
            for (int p = 0; p < nd; ++p) {
                int f; float q;
                if (p < 8) { f = dl8s[slot * 8 + p];          q = dl8q[slot * 8 + p]; }
                else       { f = dl_s[slot * MAXDIRTY + p];   q = dl_q[slot * MAXDIRTY + p]; }
                m = fmaxf(m, q * h_upd[f * 128 + c]);   // global, L2-local, rare
            }
            hz[c * 4 + s] = (deg_l[slot] > 0) ? 1.f / (1.f + __expf(-m)) : 0.f;
        } else {
            const int rz = s - 2;
            hz[c * 4 + 2 + rz] = bf2f(z16[wslot_l[e * 2 + rz] * 128 + c]);
        }
        __syncthreads();               // B1: hz ready (lgkm-only drain)

        // ---- Phase B partial: 32-chunk of both rows, weights from LDS ----
        {
            float a0 = 0.f, a1 = 0.f;
#pragma unroll
            for (int i = 0; i < 32; ++i) {
                const unsigned w = Wpk[(s * 32 + i) * 128 + c];   // 2 lanes/bank: free
                const float ws = __uint_as_float(w << 16);
                const float wr = __uint_as_float(w & 0xffff0000u);
                const float4 vz = *(const float4*)&hz[(s * 32 + i) * 4];  // broadcast
                a0 += vz.x * ws + vz.z * wr;
                a1 += vz.y * ws + vz.w * wr;
            }
            pr[(s * 2 + 0) * 128 + c] = a0;
            pr[(s * 2 + 1) * 128 + c] = a1;
        }
        __syncthreads();               // B2: partials ready

        // ---- Phase B final ----
        if (tid < 256) {
            const int r = s;
            float g = pr[(0 * 2 + r) * 128 + c] + pr[(1 * 2 + r) * 128 + c] +
                      pr[(2 * 2 + r) * 128 + c] + pr[(3 * 2 + r) * 128 + c];
            g += dtv_l[e * 2 + r] * wt_c;
            const float zv = 1.f / (1.f + __expf(-g));
            znw[r * 128 + c] = zv;
            if (!(dup && r == 0))
                z16[wslot_l[e * 2 + r] * 128 + c] = (unsigned short)rne16(zv);
        }
        __syncthreads();               // B3: znw/z16 ready

        // ---- Phase C (rare): refresh h rows in global h_upd ----
        if (nh) {
            float b0 = 0.f, b1 = 0.f;
#pragma unroll
            for (int i4 = 0; i4 < 8; ++i4) {
                const float4 wv = *(const float4*)&W_h[c * H + s * 32 + i4 * 4];
                const float4 z0 = *(const float4*)&znw[0 * 128 + s * 32 + i4 * 4];
                const float4 z1 = *(const float4*)&znw[1 * 128 + s * 32 + i4 * 4];
                b0 += z0.x * wv.x + z0.y * wv.y + z0.z * wv.z + z0.w * wv.w;
                b1 += z1.x * wv.x + z1.y * wv.y + z1.z * wv.z + z1.w * wv.w;
            }
            pr[(s * 2 + 0) * 128 + c] = b0;
            pr[(s * 2 + 1) * 128 + c] = b1;
            __syncthreads();           // B4
            if (tid < 256 && !(dup && s == 0)) {
                const float hval = pr[(0 * 2 + s) * 128 + c] + pr[(1 * 2 + s) * 128 + c] +
                                   pr[(2 * 2 + s) * 128 + c] + pr[(3 * 2 + s) * 128 + c] + bh_c;
                h_upd[wslot_l[e * 2 + s] * 128 + c] = hval;
            }
            __syncthreads();           // B5: h_upd visible for later dirty reads
        }
    }

    // ---- flush canonical slots, coalesced: lane = column ----
    for (int sl = s; sl < 128; sl += 4) {
        if (wslot_l[sl] == sl) {
            const int node = (sl & 1) ? ev_u_l[sl >> 1] : ev_v_l[sl >> 1];
            z_out[(size_t)node * H + c] = bf2f(z16[sl * 128 + c]);
        }
    }
}

// ---------------------------------------------------------------------------
extern "C" void kernel_launch(void* const* d_in, const int* in_sizes, int n_in,
                              void* d_out, int out_size, void* d_ws, size_t ws_size,
                              hipStream_t stream)
{
    const int*   u        = (const int*)d_in[0];
    const int*   v        = (const int*)d_in[1];
    const float* t        = (const float*)d_in[2];
    const int*   k        = (const int*)d_in[3];
    const int*   u_others = (const int*)d_in[4];
    const int*   v_others = (const int*)d_in[5];
    const float* A        = (const float*)d_in[6];
    const float* S        = (const float*)d_in[7];
    const float* emb      = (const float*)d_in[8];
    const float* lastt    = (const float*)d_in[9];
    const float* W_S      = (const float*)d_in[10];
    const float* W_R      = (const float*)d_in[11];
    const float* W_t      = (const float*)d_in[12];
    const float* W_h      = (const float*)d_in[13];
    const float* b_h      = (const float*)d_in[14];
    const float* psi      = (const float*)d_in[15];
    const float* W_om     = (const float*)d_in[16];
    const float* b_om     = (const float*)d_in[17];
    (void)in_sizes; (void)n_in; (void)out_size; (void)ws_size;

    float* wsf   = (float*)d_ws;
    float* h_tab = wsf;                           // N*H
    float* d0    = h_tab + (size_t)N * H;         // N
    float* d1    = d0 + N;                        // N
    float* sumv  = d1 + N;                        // 128
    float* nbre  = sumv + 128;                    // 128*MAXD
    float* Mstat = nbre + 128 * MAXD;             // 128*H
    float* dl_q  = Mstat + 128 * H;               // 128*MAXDIRTY
    float* dtv   = dl_q + 128 * MAXDIRTY;         // 128
    int*   deg   = (int*)(dtv + 128);             // 128
    int*   dcnt  = deg + 128;                     // 128
    int*   nbri  = dcnt + 128;                    // 128*MAXD
    int*   dl_s  = nbri + 128 * MAXD;             // 128*MAXDIRTY
    int*   fu    = dl_s + 128 * MAXDIRTY;         // N
    int*   zsrc  = fu + N;                        // 128
    int*   wslot = zsrc + 128;                    // 128
    int*   needh = wslot + 128;                   // 64
    int*   hneeds= needh + 64;                    // 128
    float* h_upd = (float*)(hneeds + 128);        // 128*128

    float* out    = (float*)d_out;
    float* lamout = out;            // [64]
    float* svout  = out + NEV;      // [20]
    float* z_out  = out + NEV + SS; // [N*H]

    hipFuncSetAttribute((const void*)k_seq,
                        hipFuncAttributeMaxDynamicSharedMemorySize,
                        KSEQ_LDS_BYTES);

    k_init<<<1, 256, 0, stream>>>(u, v, t, lastt, fu, zsrc, wslot, dtv, deg, dcnt, needh, hneeds);
    k_emb<<<N / RPB, 512, 0, stream>>>(emb, W_h, b_h, W_om, h_tab, z_out, d0, d1);
    k_nbr<<<128, 256, 0, stream>>>(u, v, A, S, deg, sumv, nbri, nbre);
    k_dm<<<128, 128, 0, stream>>>(deg, sumv, nbri, nbre, fu, h_tab, Mstat, dcnt, dl_s, dl_q, needh, hneeds);
    k_ls<<<SS + 1, 64, 0, stream>>>(u, v, k, u_others, v_others, d0, d1, psi, b_om, lamout, svout);
    k_seq<<<1, 512, KSEQ_LDS_BYTES, stream>>>(u, v, W_S, W_R, W_t, W_h, b_h,
                                              deg, dcnt, dl_s, dl_q, Mstat,
                                              wslot, dtv, hneeds, h_upd, z_out);
}

// Round 9
// 145.272 us; speedup vs baseline: 1.7093x; 1.7093x over previous
//
#include <hip/hip_runtime.h>
#include <math.h>

#define N 8192
#define H 128
#define NEV 64
#define SS 20
#define MAXD 512
#define MAXDIRTY 128
#define RPB 32

// ---------------------------------------------------------------------------
// k_init: per-slot dependency metadata. slot = 2e+r (r=0 -> row v[e], r=1 ->
// row u[e]). nodeofslot, fu (first updater, for k_dm's static test),
// zdep[slot] = latest updater slot of node strictly before event e (else -1),
// lastup[slot] = 1 iff slot is the final updater of its node (writes z_out;
// for dup events the odd/u slot wins automatically), dtv = crossed dt.
// Zeroes deg/dcnt/hpub/donebits.
// ---------------------------------------------------------------------------
__global__ __launch_bounds__(256) void k_init(
    const int* __restrict__ u, const int* __restrict__ v,
    const float* __restrict__ t, const float* __restrict__ lastt,
    int* __restrict__ fu, int* __restrict__ nodeofslot,
    int* __restrict__ zdep, int* __restrict__ lastup,
    float* __restrict__ dtv, int* __restrict__ deg, int* __restrict__ dcnt,
    int* __restrict__ hpub, unsigned long long* __restrict__ donebits)
{
    __shared__ int fuL[N];       // 32 KB
    __shared__ int nodL[2 * NEV];
    const int tid = threadIdx.x;
    for (int i = tid; i < N; i += 256) fuL[i] = 0x7FFFFFFF;
    if (tid < 128) { deg[tid] = 0; dcnt[tid] = 0; hpub[tid] = 0; }
    if (tid == 0) donebits[0] = 0ull;
    if (tid < 2 * NEV) {
        const int e = tid >> 1, i = tid & 1;
        nodL[tid] = i ? u[e] : v[e];        // slot 2e -> v[e], 2e+1 -> u[e]
        nodeofslot[tid] = nodL[tid];
    }
    __syncthreads();
    if (tid < 2 * NEV) atomicMin(&fuL[nodL[tid]], tid);
    __syncthreads();
    for (int i = tid; i < N; i += 256) fu[i] = fuL[i];
    if (tid < 2 * NEV) {
        const int slot = tid, e = slot >> 1, i = slot & 1;
        const int node = nodL[slot];
        int zd = -1;
        for (int j = 2 * e - 1; j >= 0; --j)
            if (nodL[j] == node) { zd = j; break; }
        zdep[slot] = zd;
        int lu = 1;
        for (int j = slot + 1; j < 2 * NEV; ++j)
            if (nodL[j] == node) { lu = 0; break; }
        lastup[slot] = lu;
        const int dtn = i ? v[e] : u[e];     // crossed: row v uses let[u], row u let[v]
        int pt = -1;
        for (int e2 = e - 1; e2 >= 0; --e2)
            if (u[e2] == dtn || v[e2] == dtn) { pt = e2; break; }
        const float lv = (pt >= 0) ? t[pt] : lastt[dtn];
        dtv[slot] = t[e] - lv;
    }
}

// ---------------------------------------------------------------------------
// k_emb: h_tab = emb @ W_h.T + b_h ; z_out = emb copy ; d0/d1 rate dots.
// [byte-identical to rounds 6-8, passed repeatedly]
// ---------------------------------------------------------------------------
__global__ __launch_bounds__(512) void k_emb(
    const float* __restrict__ emb, const float* __restrict__ W_h,
    const float* __restrict__ b_h, const float* __restrict__ W_om,
    float* __restrict__ h_tab, float* __restrict__ z_out,
    float* __restrict__ d0, float* __restrict__ d1)
{
    const int tid = threadIdx.x;
    const int c = tid & 127;
    const int s = tid >> 7;             // 0..3
    const int r0 = blockIdx.x * RPB;

    __shared__ __align__(16) float z4[4 * 128];
    __shared__ float pr[8 * 128];

    float whr[32];
#pragma unroll
    for (int i = 0; i < 32; ++i) whr[i] = W_h[c * H + s * 32 + i];
    const float bh_c = b_h[c];

    const int lane = tid & 63;
    const int wid = tid >> 6;
    const int kof = (wid >= 4) ? 256 : 0;
    const float wk_l = W_om[kof + lane]      + W_om[kof + 128 + lane];
    const float wk_h = W_om[kof + 64 + lane] + W_om[kof + 192 + lane];

    for (int b = 0; b < RPB / 4; ++b) {
        const int rbase = r0 + b * 4;
        __syncthreads();
        const float zv = emb[(size_t)rbase * H + tid];
        z4[tid] = zv;
        z_out[(size_t)rbase * H + tid] = zv;
        __syncthreads();

#pragma unroll
        for (int rr = 0; rr < 4; ++rr) {
            float a = 0.f;
#pragma unroll
            for (int i4 = 0; i4 < 8; ++i4) {
                const float4 zz = *(const float4*)&z4[rr * 128 + s * 32 + i4 * 4];
                a += zz.x * whr[i4 * 4] + zz.y * whr[i4 * 4 + 1] +
                     zz.z * whr[i4 * 4 + 2] + zz.w * whr[i4 * 4 + 3];
            }
            pr[(s * 4 + rr) * 128 + c] = a;
        }
        {
            const int rr = wid & 3;
            float val = z4[rr * 128 + lane] * wk_l + z4[rr * 128 + 64 + lane] * wk_h;
#pragma unroll
            for (int off = 32; off > 0; off >>= 1) val += __shfl_xor(val, off);
            if (lane == 0) {
                if (wid < 4) d0[rbase + rr] = val;
                else         d1[rbase + rr] = val;
            }
        }
        __syncthreads();
        {
            const int rr = s;
            const float h = pr[(0 * 4 + rr) * 128 + c] + pr[(1 * 4 + rr) * 128 + c] +
                            pr[(2 * 4 + rr) * 128 + c] + pr[(3 * 4 + rr) * 128 + c] + bh_c;
            h_tab[(size_t)(rbase + rr) * H + c] = h;
        }
    }
}

// ---------------------------------------------------------------------------
// k_nbr: compact neighbor lists. [byte-identical to rounds 6-8]
// ---------------------------------------------------------------------------
__global__ __launch_bounds__(256) void k_nbr(
    const int* __restrict__ u, const int* __restrict__ v,
    const float* __restrict__ A, const float* __restrict__ S,
    int* __restrict__ deg, float* __restrict__ sumv,
    int* __restrict__ nbr_i, float* __restrict__ nbr_e)
{
    const int slot = blockIdx.x;
    const int e = slot >> 1, side = slot & 1;
    const int row = (side == 0) ? v[e] : u[e];
    const size_t base = (size_t)row * N;
    const int tid = threadIdx.x;
    float lsum = 0.f;
    for (int j = tid; j < N; j += 256) {
        if (A[base + j] > 0.f) {
            const float ev = expf(S[base + j]);
            lsum += ev;
            const int p = atomicAdd(&deg[slot], 1);
            if (p < MAXD) {
                nbr_i[slot * MAXD + p] = j;
                nbr_e[slot * MAXD + p] = ev;
            }
        }
    }
    __shared__ float rs[256];
    rs[tid] = lsum;
    __syncthreads();
    for (int off = 128; off > 0; off >>= 1) {
        if (tid < off) rs[tid] += rs[tid + off];
        __syncthreads();
    }
    if (tid == 0) sumv[slot] = rs[0];
}

// ---------------------------------------------------------------------------
// k_dm: Mstat over static neighbors (fu[j] >= 2e, h from h_tab) + dirty list
// where each entry stores the LATEST-updater dep slot of the dirty node
// (< 2e) and marks hpub[dep] so that event publishes h_slot[dep].
// ---------------------------------------------------------------------------
__global__ __launch_bounds__(128) void k_dm(
    const int* __restrict__ deg, const float* __restrict__ sumv,
    const int* __restrict__ nbr_i, const float* __restrict__ nbr_e,
    const int* __restrict__ fu, const float* __restrict__ h_tab,
    const int* __restrict__ nodeofslot,
    float* __restrict__ Mstat, int* __restrict__ dcnt,
    int* __restrict__ dl_s, float* __restrict__ dl_q,
    int* __restrict__ hpub)
{
    const int slot = blockIdx.x;
    const int e = slot >> 1;
    const int c = threadIdx.x;
    const int d = min(deg[slot], MAXD);
    const float rinv = 1.f / (sumv[slot] + 1e-7f);
    float m = -INFINITY;
    for (int j0 = 0; j0 < d; ++j0) {
        const int j = nbr_i[slot * MAXD + j0];
        if (fu[j] >= 2 * e)
            m = fmaxf(m, nbr_e[slot * MAXD + j0] * rinv * h_tab[(size_t)j * H + c]);
    }
    Mstat[slot * H + c] = m;
    for (int j0 = c; j0 < d; j0 += 128) {
        const int j = nbr_i[slot * MAXD + j0];
        if (fu[j] < 2 * e) {
            int dep = -1;                              // latest updater < 2e
            for (int s2 = 2 * e - 1; s2 >= 0; --s2)
                if (nodeofslot[s2] == j) { dep = s2; break; }
            const int p = atomicAdd(&dcnt[slot], 1);
            if (p < MAXDIRTY) {
                dl_s[slot * MAXDIRTY + p] = dep;
                dl_q[slot * MAXDIRTY + p] = nbr_e[slot * MAXD + j0] * rinv;
            }
            hpub[dep] = 1;
        }
    }
}

// ---------------------------------------------------------------------------
// k_ls: lam (block 0) + survival (blocks 1..SS). [byte-identical to rounds 6-8]
// ---------------------------------------------------------------------------
__global__ __launch_bounds__(64) void k_ls(
    const int* __restrict__ u, const int* __restrict__ v, const int* __restrict__ kk,
    const int* __restrict__ u_o, const int* __restrict__ v_o,
    const float* __restrict__ d0, const float* __restrict__ d1,
    const float* __restrict__ psi, const float* __restrict__ b_om,
    float* __restrict__ lamout, float* __restrict__ svout)
{
    const int b = threadIdx.x;
    if (blockIdx.x == 0) {
        if (b < NEV) {
            const int kv = kk[b];
            const float* dk = kv ? d1 : d0;
            const float g = 0.5f * (dk[u[b]] + dk[v[b]]) + b_om[kv];
            const float ps = psi[kv];
            const float x = fminf(75.f, fmaxf(-75.f, g / ps));
            lamout[b] = ps * log1pf(expf(x));
        }
    } else {
        const int s = blockIdx.x - 1;
        const float p0 = psi[0], p1 = psi[1], bo0 = b_om[0], bo1 = b_om[1];
        const int vo = v_o[b * SS + s], uo = u_o[b * SS + s];
        float g, x;
        g = 0.5f * (d0[u[b]] + d0[vo]) + bo0; x = fminf(75.f, fmaxf(-75.f, g / p0));
        const float ru0 = p0 * log1pf(expf(x));
        g = 0.5f * (d1[u[b]] + d1[vo]) + bo1; x = fminf(75.f, fmaxf(-75.f, g / p1));
        const float ru1 = p1 * log1pf(expf(x));
        g = 0.5f * (d1[v[b]] + d1[uo]) + bo1; x = fminf(75.f, fmaxf(-75.f, g / p1));
        const float rv1 = p1 * log1pf(expf(x));
        float val = 2.f * (ru0 + ru1) + rv1;
#pragma unroll
        for (int off = 32; off > 0; off >>= 1) val += __shfl_xor(val, off);
        if (b == 0) svout[s] = val / (float)SS;
    }
}

// ---------------------------------------------------------------------------
// k_par: one block per EVENT, 256 threads (r = tid>>7 in {0:v-row, 1:u-row},
// c = tid&127). True deps (z latest-updater + dirty-h latest-updater, both
// precomputed) enforced via a device-scope done-bitmap: producers atomicOr
// their bit with RELEASE after a block-wide fence; consumers acquire-spin.
// Per-slot versioned storage z_slot/h_slot (written once, by the owning
// event) removes all WAR hazards. Expected chain depth ~2 on random pairs.
// ---------------------------------------------------------------------------
__global__ __launch_bounds__(256) void k_par(
    const float* __restrict__ emb,
    const float* __restrict__ W_S, const float* __restrict__ W_R,
    const float* __restrict__ W_t, const float* __restrict__ W_h,
    const float* __restrict__ b_h,
    const int* __restrict__ deg, const int* __restrict__ dcnt,
    const int* __restrict__ dl_s, const float* __restrict__ dl_q,
    const float* __restrict__ Mstat, const float* __restrict__ dtv,
    const int* __restrict__ zdep, const int* __restrict__ lastup,
    const int* __restrict__ hpub, const int* __restrict__ nodeofslot,
    float* __restrict__ z_slot, float* __restrict__ h_slot,
    unsigned long long* __restrict__ donebits,
    float* __restrict__ z_out)
{
    const int e = blockIdx.x;
    const int tid = threadIdx.x;
    const int r = tid >> 7;             // wave-uniform (waves 0-1: r=0, 2-3: r=1)
    const int c = tid & 127;
    const int slot = 2 * e + r;

    __shared__ __align__(16) float hs_s[2][128];
    __shared__ __align__(16) float zz_s[2][128];
    __shared__ __align__(16) float zn_s[2][128];
    __shared__ unsigned long long need_s;

    // ---- build need-mask and spin (thread 0), then per-thread acquire ----
    if (tid == 0) {
        unsigned long long need = 0ull;
        for (int rr = 0; rr < 2; ++rr) {
            const int sl = 2 * e + rr;
            const int zd = zdep[sl];
            if (zd >= 0) need |= 1ull << (zd >> 1);
            const int dn = min(dcnt[sl], MAXDIRTY);
            for (int p = 0; p < dn; ++p)
                need |= 1ull << (dl_s[sl * MAXDIRTY + p] >> 1);
        }
        need_s = need;
        if (need) {
            while ((__hip_atomic_load(donebits, __ATOMIC_ACQUIRE,
                                      __HIP_MEMORY_SCOPE_AGENT) & need) != need)
                __builtin_amdgcn_s_sleep(2);
        }
    }
    __syncthreads();
    if (need_s) {   // per-thread acquire: invalidate stale cache lines on this CU
        unsigned long long db = __hip_atomic_load(donebits, __ATOMIC_ACQUIRE,
                                                  __HIP_MEMORY_SCOPE_AGENT);
        (void)db;
    }

    // ---- Phase A: hs (Mstat static max + dirty via h_slot) and z (versioned) ----
    {
        float m = Mstat[slot * H + c];
        const int dn = min(dcnt[slot], MAXDIRTY);
        for (int p = 0; p < dn; ++p) {
            const int ds = dl_s[slot * MAXDIRTY + p];
            const float q = dl_q[slot * MAXDIRTY + p];
            m = fmaxf(m, q * h_slot[ds * H + c]);
        }
        hs_s[r][c] = (deg[slot] > 0) ? 1.f / (1.f + __expf(-m)) : 0.f;
        const int zd = zdep[slot];
        zz_s[r][c] = (zd >= 0) ? z_slot[zd * H + c]
                               : emb[(size_t)nodeofslot[slot] * H + c];
    }
    __syncthreads();

    // ---- Phase B: g = hs.W_S[c] + z.W_R[c] + dt*W_t[c]; sigmoid ----
    float g = 0.f;
    {
        const float4* ws4 = (const float4*)(W_S + (size_t)c * H);
        const float4* wr4 = (const float4*)(W_R + (size_t)c * H);
#pragma unroll
        for (int i = 0; i < 32; ++i) {
            const float4 a = ws4[i];
            const float4 b = wr4[i];
            const float4 hh = *(const float4*)&hs_s[r][4 * i];   // LDS broadcast
            const float4 zz = *(const float4*)&zz_s[r][4 * i];
            g += hh.x * a.x + hh.y * a.y + hh.z * a.z + hh.w * a.w +
                 zz.x * b.x + zz.y * b.y + zz.z * b.z + zz.w * b.w;
        }
    }
    g += dtv[slot] * W_t[c];
    const float zv = 1.f / (1.f + __expf(-g));
    zn_s[r][c] = zv;
    z_slot[slot * H + c] = zv;                      // versioned publish (z)
    if (lastup[slot])                               // final updater writes output
        z_out[(size_t)nodeofslot[slot] * H + c] = zv;
    __syncthreads();                                // zn_s ready for phase C

    // ---- Phase C: publish h_slot[slot] iff some later event dirty-reads it ----
    if (hpub[slot]) {                               // wave-uniform branch
        float h = 0.f;
        const float4* wh4 = (const float4*)(W_h + (size_t)c * H);
#pragma unroll
        for (int i = 0; i < 32; ++i) {
            const float4 a = wh4[i];
            const float4 zz = *(const float4*)&zn_s[r][4 * i];
            h += zz.x * a.x + zz.y * a.y + zz.z * a.z + zz.w * a.w;
        }
        h_slot[slot * H + c] = h + b_h[c];
    }

    // ---- release: all block writes drained (barrier), fenced, then bit set ----
    __syncthreads();
    if (tid == 0) {
        __threadfence();                            // agent-scope write visibility
        __hip_atomic_fetch_or(donebits, 1ull << e, __ATOMIC_RELEASE,
                              __HIP_MEMORY_SCOPE_AGENT);
    }
}

// ---------------------------------------------------------------------------
extern "C" void kernel_launch(void* const* d_in, const int* in_sizes, int n_in,
                              void* d_out, int out_size, void* d_ws, size_t ws_size,
                              hipStream_t stream)
{
    const int*   u        = (const int*)d_in[0];
    const int*   v        = (const int*)d_in[1];
    const float* t        = (const float*)d_in[2];
    const int*   k        = (const int*)d_in[3];
    const int*   u_others = (const int*)d_in[4];
    const int*   v_others = (const int*)d_in[5];
    const float* A        = (const float*)d_in[6];
    const float* S        = (const float*)d_in[7];
    const float* emb      = (const float*)d_in[8];
    const float* lastt    = (const float*)d_in[9];
    const float* W_S      = (const float*)d_in[10];
    const float* W_R      = (const float*)d_in[11];
    const float* W_t      = (const float*)d_in[12];
    const float* W_h      = (const float*)d_in[13];
    const float* b_h      = (const float*)d_in[14];
    const float* psi      = (const float*)d_in[15];
    const float* W_om     = (const float*)d_in[16];
    const float* b_om     = (const float*)d_in[17];
    (void)in_sizes; (void)n_in; (void)out_size; (void)ws_size;

    float* wsf    = (float*)d_ws;
    float* h_tab  = wsf;                            // N*H
    float* d0     = h_tab + (size_t)N * H;          // N
    float* d1     = d0 + N;                         // N
    float* sumv   = d1 + N;                         // 128
    float* nbre   = sumv + 128;                     // 128*MAXD
    float* Mstat  = nbre + 128 * MAXD;              // 128*H
    float* dl_q   = Mstat + 128 * H;                // 128*MAXDIRTY
    float* dtv    = dl_q + 128 * MAXDIRTY;          // 128
    float* z_slot = dtv + 128;                      // 128*H
    float* h_slot = z_slot + 128 * H;               // 128*H
    int*   deg    = (int*)(h_slot + 128 * H);       // 128
    int*   dcnt   = deg + 128;                      // 128
    int*   nbri   = dcnt + 128;                     // 128*MAXD
    int*   dl_s   = nbri + 128 * MAXD;              // 128*MAXDIRTY
    int*   fu     = dl_s + 128 * MAXDIRTY;          // N
    int*   nodeofslot = fu + N;                     // 128
    int*   zdep   = nodeofslot + 128;               // 128
    int*   lastup = zdep + 128;                     // 128
    int*   hpub   = lastup + 128;                   // 128
    unsigned long long* donebits = (unsigned long long*)(hpub + 128);  // 1 (8B-aligned)

    float* out    = (float*)d_out;
    float* lamout = out;            // [64]
    float* svout  = out + NEV;      // [20]
    float* z_out  = out + NEV + SS; // [N*H]

    k_init<<<1, 256, 0, stream>>>(u, v, t, lastt, fu, nodeofslot, zdep, lastup,
                                  dtv, deg, dcnt, hpub, donebits);
    k_emb<<<N / RPB, 512, 0, stream>>>(emb, W_h, b_h, W_om, h_tab, z_out, d0, d1);
    k_nbr<<<128, 256, 0, stream>>>(u, v, A, S, deg, sumv, nbri, nbre);
    k_dm<<<128, 128, 0, stream>>>(deg, sumv, nbri, nbre, fu, h_tab, nodeofslot,
                                  Mstat, dcnt, dl_s, dl_q, hpub);
    k_ls<<<SS + 1, 64, 0, stream>>>(u, v, k, u_others, v_others, d0, d1, psi, b_om,
                                    lamout, svout);
    k_par<<<NEV, 256, 0, stream>>>(emb, W_S, W_R, W_t, W_h, b_h,
                                   deg, dcnt, dl_s, dl_q, Mstat, dtv,
                                   zdep, lastup, hpub, nodeofslot,
                                   z_slot, h_slot, donebits, z_out);
}

// Round 13
// 143.429 us; speedup vs baseline: 1.7313x; 1.0129x over previous
//
#include <hip/hip_runtime.h>
#include <math.h>

#define N 8192
#define H 128
#define NEV 64
#define SS 20
#define MAXD 512
#define MAXDIRTY 128
#define RPB 32
#define SPIN_GUARD (1 << 18)   // safety valve: converts protocol bug into absmax failure

// ---------------------------------------------------------------------------
// k_init: per-slot dependency metadata (round 9) plus consumed[e] seeding
// from zdep. Zeroes deg/dcnt/hpub/consumed/donebits.
// ---------------------------------------------------------------------------
__global__ __launch_bounds__(256) void k_init(
    const int* __restrict__ u, const int* __restrict__ v,
    const float* __restrict__ t, const float* __restrict__ lastt,
    int* __restrict__ fu, int* __restrict__ nodeofslot,
    int* __restrict__ zdep, int* __restrict__ lastup,
    float* __restrict__ dtv, int* __restrict__ deg, int* __restrict__ dcnt,
    int* __restrict__ hpub, int* __restrict__ consumed,
    unsigned long long* __restrict__ donebits)
{
    __shared__ int fuL[N];       // 32 KB
    __shared__ int nodL[2 * NEV];
    const int tid = threadIdx.x;
    for (int i = tid; i < N; i += 256) fuL[i] = 0x7FFFFFFF;
    if (tid < 128) { deg[tid] = 0; dcnt[tid] = 0; hpub[tid] = 0; }
    if (tid < NEV) consumed[tid] = 0;
    if (tid == 0) donebits[0] = 0ull;
    if (tid < 2 * NEV) {
        const int e = tid >> 1, i = tid & 1;
        nodL[tid] = i ? u[e] : v[e];        // slot 2e -> v[e], 2e+1 -> u[e]
        nodeofslot[tid] = nodL[tid];
    }
    __syncthreads();
    if (tid < 2 * NEV) atomicMin(&fuL[nodL[tid]], tid);
    __syncthreads();
    for (int i = tid; i < N; i += 256) fu[i] = fuL[i];
    if (tid < 2 * NEV) {
        const int slot = tid, e = slot >> 1, i = slot & 1;
        const int node = nodL[slot];
        int zd = -1;
        for (int j = 2 * e - 1; j >= 0; --j)
            if (nodL[j] == node) { zd = j; break; }
        zdep[slot] = zd;
        if (zd >= 0) consumed[zd >> 1] = 1;   // z of event zd>>1 is consumed
        int lu = 1;
        for (int j = slot + 1; j < 2 * NEV; ++j)
            if (nodL[j] == node) { lu = 0; break; }
        lastup[slot] = lu;
        const int dtn = i ? v[e] : u[e];     // crossed: row v uses let[u], row u let[v]
        int pt = -1;
        for (int e2 = e - 1; e2 >= 0; --e2)
            if (u[e2] == dtn || v[e2] == dtn) { pt = e2; break; }
        const float lv = (pt >= 0) ? t[pt] : lastt[dtn];
        dtv[slot] = t[e] - lv;
    }
}

// ---------------------------------------------------------------------------
// k_emb: h_tab = emb @ W_h.T + b_h ; z_out = emb copy ; d0/d1 rate dots.
// [byte-identical to round 9]
// ---------------------------------------------------------------------------
__global__ __launch_bounds__(512) void k_emb(
    const float* __restrict__ emb, const float* __restrict__ W_h,
    const float* __restrict__ b_h, const float* __restrict__ W_om,
    float* __restrict__ h_tab, float* __restrict__ z_out,
    float* __restrict__ d0, float* __restrict__ d1)
{
    const int tid = threadIdx.x;
    const int c = tid & 127;
    const int s = tid >> 7;             // 0..3
    const int r0 = blockIdx.x * RPB;

    __shared__ __align__(16) float z4[4 * 128];
    __shared__ float pr[8 * 128];

    float whr[32];
#pragma unroll
    for (int i = 0; i < 32; ++i) whr[i] = W_h[c * H + s * 32 + i];
    const float bh_c = b_h[c];

    const int lane = tid & 63;
    const int wid = tid >> 6;
    const int kof = (wid >= 4) ? 256 : 0;
    const float wk_l = W_om[kof + lane]      + W_om[kof + 128 + lane];
    const float wk_h = W_om[kof + 64 + lane] + W_om[kof + 192 + lane];

    for (int b = 0; b < RPB / 4; ++b) {
        const int rbase = r0 + b * 4;
        __syncthreads();
        const float zv = emb[(size_t)rbase * H + tid];
        z4[tid] = zv;
        z_out[(size_t)rbase * H + tid] = zv;
        __syncthreads();

#pragma unroll
        for (int rr = 0; rr < 4; ++rr) {
            float a = 0.f;
#pragma unroll
            for (int i4 = 0; i4 < 8; ++i4) {
                const float4 zz = *(const float4*)&z4[rr * 128 + s * 32 + i4 * 4];
                a += zz.x * whr[i4 * 4] + zz.y * whr[i4 * 4 + 1] +
                     zz.z * whr[i4 * 4 + 2] + zz.w * whr[i4 * 4 + 3];
            }
            pr[(s * 4 + rr) * 128 + c] = a;
        }
        {
            const int rr = wid & 3;
            float val = z4[rr * 128 + lane] * wk_l + z4[rr * 128 + 64 + lane] * wk_h;
#pragma unroll
            for (int off = 32; off > 0; off >>= 1) val += __shfl_xor(val, off);
            if (lane == 0) {
                if (wid < 4) d0[rbase + rr] = val;
                else         d1[rbase + rr] = val;
            }
        }
        __syncthreads();
        {
            const int rr = s;
            const float h = pr[(0 * 4 + rr) * 128 + c] + pr[(1 * 4 + rr) * 128 + c] +
                            pr[(2 * 4 + rr) * 128 + c] + pr[(3 * 4 + rr) * 128 + c] + bh_c;
            h_tab[(size_t)(rbase + rr) * H + c] = h;
        }
    }
}

// ---------------------------------------------------------------------------
// k_nbr: compact neighbor lists. [byte-identical to round 9]
// ---------------------------------------------------------------------------
__global__ __launch_bounds__(256) void k_nbr(
    const int* __restrict__ u, const int* __restrict__ v,
    const float* __restrict__ A, const float* __restrict__ S,
    int* __restrict__ deg, float* __restrict__ sumv,
    int* __restrict__ nbr_i, float* __restrict__ nbr_e)
{
    const int slot = blockIdx.x;
    const int e = slot >> 1, side = slot & 1;
    const int row = (side == 0) ? v[e] : u[e];
    const size_t base = (size_t)row * N;
    const int tid = threadIdx.x;
    float lsum = 0.f;
    for (int j = tid; j < N; j += 256) {
        if (A[base + j] > 0.f) {
            const float ev = expf(S[base + j]);
            lsum += ev;
            const int p = atomicAdd(&deg[slot], 1);
            if (p < MAXD) {
                nbr_i[slot * MAXD + p] = j;
                nbr_e[slot * MAXD + p] = ev;
            }
        }
    }
    __shared__ float rs[256];
    rs[tid] = lsum;
    __syncthreads();
    for (int off = 128; off > 0; off >>= 1) {
        if (tid < off) rs[tid] += rs[tid + off];
        __syncthreads();
    }
    if (tid == 0) sumv[slot] = rs[0];
}

// ---------------------------------------------------------------------------
// k_dm: Mstat over static neighbors + dirty list with latest-updater dep
// slots; marks hpub[dep] and consumed[dep>>1]. [round 11]
// ---------------------------------------------------------------------------
__global__ __launch_bounds__(128) void k_dm(
    const int* __restrict__ deg, const float* __restrict__ sumv,
    const int* __restrict__ nbr_i, const float* __restrict__ nbr_e,
    const int* __restrict__ fu, const float* __restrict__ h_tab,
    const int* __restrict__ nodeofslot,
    float* __restrict__ Mstat, int* __restrict__ dcnt,
    int* __restrict__ dl_s, float* __restrict__ dl_q,
    int* __restrict__ hpub, int* __restrict__ consumed)
{
    const int slot = blockIdx.x;
    const int e = slot >> 1;
    const int c = threadIdx.x;
    const int d = min(deg[slot], MAXD);
    const float rinv = 1.f / (sumv[slot] + 1e-7f);
    float m = -INFINITY;
    for (int j0 = 0; j0 < d; ++j0) {
        const int j = nbr_i[slot * MAXD + j0];
        if (fu[j] >= 2 * e)
            m = fmaxf(m, nbr_e[slot * MAXD + j0] * rinv * h_tab[(size_t)j * H + c]);
    }
    Mstat[slot * H + c] = m;
    for (int j0 = c; j0 < d; j0 += 128) {
        const int j = nbr_i[slot * MAXD + j0];
        if (fu[j] < 2 * e) {
            int dep = -1;                              // latest updater < 2e
            for (int s2 = 2 * e - 1; s2 >= 0; --s2)
                if (nodeofslot[s2] == j) { dep = s2; break; }
            const int p = atomicAdd(&dcnt[slot], 1);
            if (p < MAXDIRTY) {
                dl_s[slot * MAXDIRTY + p] = dep;
                dl_q[slot * MAXDIRTY + p] = nbr_e[slot * MAXD + j0] * rinv;
            }
            hpub[dep] = 1;
            consumed[dep >> 1] = 1;                    // release needed for that event
        }
    }
}

// ---------------------------------------------------------------------------
// k_ls: lam (block 0) + survival (blocks 1..SS). [byte-identical to round 9]
// ---------------------------------------------------------------------------
__global__ __launch_bounds__(64) void k_ls(
    const int* __restrict__ u, const int* __restrict__ v, const int* __restrict__ kk,
    const int* __restrict__ u_o, const int* __restrict__ v_o,
    const float* __restrict__ d0, const float* __restrict__ d1,
    const float* __restrict__ psi, const float* __restrict__ b_om,
    float* __restrict__ lamout, float* __restrict__ svout)
{
    const int b = threadIdx.x;
    if (blockIdx.x == 0) {
        if (b < NEV) {
            const int kv = kk[b];
            const float* dk = kv ? d1 : d0;
            const float g = 0.5f * (dk[u[b]] + dk[v[b]]) + b_om[kv];
            const float ps = psi[kv];
            const float x = fminf(75.f, fmaxf(-75.f, g / ps));
            lamout[b] = ps * log1pf(expf(x));
        }
    } else {
        const int s = blockIdx.x - 1;
        const float p0 = psi[0], p1 = psi[1], bo0 = b_om[0], bo1 = b_om[1];
        const int vo = v_o[b * SS + s], uo = u_o[b * SS + s];
        float g, x;
        g = 0.5f * (d0[u[b]] + d0[vo]) + bo0; x = fminf(75.f, fmaxf(-75.f, g / p0));
        const float ru0 = p0 * log1pf(expf(x));
        g = 0.5f * (d1[u[b]] + d1[vo]) + bo1; x = fminf(75.f, fmaxf(-75.f, g / p1));
        const float ru1 = p1 * log1pf(expf(x));
        g = 0.5f * (d1[v[b]] + d1[uo]) + bo1; x = fminf(75.f, fmaxf(-75.f, g / p1));
        const float rv1 = p1 * log1pf(expf(x));
        float val = 2.f * (ru0 + ru1) + rv1;
#pragma unroll
        for (int off = 32; off > 0; off >>= 1) val += __shfl_xor(val, off);
        if (b == 0) svout[s] = val / (float)SS;
    }
}

// ---------------------------------------------------------------------------
// k_par: one block per event (round-9 proven protocol). Release skipped when
// consumed[e]==0 (round-11 change). Spin loop BOUNDED — a protocol hole
// produces a visible absmax failure instead of a dead container.
// ---------------------------------------------------------------------------
__global__ __launch_bounds__(256) void k_par(
    const float* __restrict__ emb,
    const float* __restrict__ W_S, const float* __restrict__ W_R,
    const float* __restrict__ W_t, const float* __restrict__ W_h,
    const float* __restrict__ b_h,
    const int* __restrict__ deg, const int* __restrict__ dcnt,
    const int* __restrict__ dl_s, const float* __restrict__ dl_q,
    const float* __restrict__ Mstat, const float* __restrict__ dtv,
    const int* __restrict__ zdep, const int* __restrict__ lastup,
    const int* __restrict__ hpub, const int* __restrict__ nodeofslot,
    const int* __restrict__ consumed,
    float* __restrict__ z_slot, float* __restrict__ h_slot,
    unsigned long long* __restrict__ donebits,
    float* __restrict__ z_out)
{
    const int e = blockIdx.x;
    const int tid = threadIdx.x;
    const int r = tid >> 7;             // wave-uniform (waves 0-1: r=0, 2-3: r=1)
    const int c = tid & 127;
    const int slot = 2 * e + r;

    __shared__ __align__(16) float hs_s[2][128];
    __shared__ __align__(16) float zz_s[2][128];
    __shared__ __align__(16) float zn_s[2][128];
    __shared__ unsigned long long need_s;

    // ---- build need-mask and spin (thread 0), then per-thread acquire ----
    if (tid == 0) {
        unsigned long long need = 0ull;
        for (int rr = 0; rr < 2; ++rr) {
            const int sl = 2 * e + rr;
            const int zd = zdep[sl];
            if (zd >= 0) need |= 1ull << (zd >> 1);
            const int dn = min(dcnt[sl], MAXDIRTY);
            for (int p = 0; p < dn; ++p)
                need |= 1ull << (dl_s[sl * MAXDIRTY + p] >> 1);
        }
        need_s = need;
        if (need) {
            int guard = 0;
            while ((__hip_atomic_load(donebits, __ATOMIC_ACQUIRE,
                                      __HIP_MEMORY_SCOPE_AGENT) & need) != need) {
                __builtin_amdgcn_s_sleep(2);
                if (++guard > SPIN_GUARD) break;       // safety valve
            }
        }
    }
    __syncthreads();
    if (need_s) {   // per-thread acquire: invalidate stale cache lines on this CU
        unsigned long long db = __hip_atomic_load(donebits, __ATOMIC_ACQUIRE,
                                                  __HIP_MEMORY_SCOPE_AGENT);
        (void)db;
    }

    // ---- Phase A: hs (Mstat static max + dirty via h_slot) and z (versioned) ----
    {
        float m = Mstat[slot * H + c];
        const int dn = min(dcnt[slot], MAXDIRTY);
        for (int p = 0; p < dn; ++p) {
            const int ds = dl_s[slot * MAXDIRTY + p];
            const float q = dl_q[slot * MAXDIRTY + p];
            m = fmaxf(m, q * h_slot[ds * H + c]);
        }
        hs_s[r][c] = (deg[slot] > 0) ? 1.f / (1.f + __expf(-m)) : 0.f;
        const int zd = zdep[slot];
        zz_s[r][c] = (zd >= 0) ? z_slot[zd * H + c]
                               : emb[(size_t)nodeofslot[slot] * H + c];
    }
    __syncthreads();

    // ---- Phase B: g = hs.W_S[c] + z.W_R[c] + dt*W_t[c]; sigmoid ----
    float g = 0.f;
    {
        const float4* ws4 = (const float4*)(W_S + (size_t)c * H);
        const float4* wr4 = (const float4*)(W_R + (size_t)c * H);
#pragma unroll
        for (int i = 0; i < 32; ++i) {
            const float4 a = ws4[i];
            const float4 b = wr4[i];
            const float4 hh = *(const float4*)&hs_s[r][4 * i];   // LDS broadcast
            const float4 zz = *(const float4*)&zz_s[r][4 * i];
            g += hh.x * a.x + hh.y * a.y + hh.z * a.z + hh.w * a.w +
                 zz.x * b.x + zz.y * b.y + zz.z * b.z + zz.w * b.w;
        }
    }
    g += dtv[slot] * W_t[c];
    const float zv = 1.f / (1.f + __expf(-g));
    zn_s[r][c] = zv;
    z_slot[slot * H + c] = zv;                      // versioned publish (z)
    if (lastup[slot])                               // final updater writes output
        z_out[(size_t)nodeofslot[slot] * H + c] = zv;
    __syncthreads();                                // zn_s ready for phase C

    // ---- Phase C: publish h_slot[slot] iff some later event dirty-reads it ----
    if (hpub[slot]) {                               // wave-uniform branch
        float h = 0.f;
        const float4* wh4 = (const float4*)(W_h + (size_t)c * H);
#pragma unroll
        for (int i = 0; i < 32; ++i) {
            const float4 a = wh4[i];
            const float4 zz = *(const float4*)&zn_s[r][4 * i];
            h += zz.x * a.x + zz.y * a.y + zz.z * a.z + zz.w * a.w;
        }
        h_slot[slot * H + c] = h + b_h[c];
    }

    // ---- release only when someone will consume this event's outputs ----
    __syncthreads();
    if (tid == 0 && consumed[e]) {
        __threadfence();                            // agent-scope write visibility
        __hip_atomic_fetch_or(donebits, 1ull << e, __ATOMIC_RELEASE,
                              __HIP_MEMORY_SCOPE_AGENT);
    }
}

// ---------------------------------------------------------------------------
extern "C" void kernel_launch(void* const* d_in, const int* in_sizes, int n_in,
                              void* d_out, int out_size, void* d_ws, size_t ws_size,
                              hipStream_t stream)
{
    const int*   u        = (const int*)d_in[0];
    const int*   v        = (const int*)d_in[1];
    const float* t        = (const float*)d_in[2];
    const int*   k        = (const int*)d_in[3];
    const int*   u_others = (const int*)d_in[4];
    const int*   v_others = (const int*)d_in[5];
    const float* A        = (const float*)d_in[6];
    const float* S        = (const float*)d_in[7];
    const float* emb      = (const float*)d_in[8];
    const float* lastt    = (const float*)d_in[9];
    const float* W_S      = (const float*)d_in[10];
    const float* W_R      = (const float*)d_in[11];
    const float* W_t      = (const float*)d_in[12];
    const float* W_h      = (const float*)d_in[13];
    const float* b_h      = (const float*)d_in[14];
    const float* psi      = (const float*)d_in[15];
    const float* W_om     = (const float*)d_in[16];
    const float* b_om     = (const float*)d_in[17];
    (void)in_sizes; (void)n_in; (void)out_size; (void)ws_size;

    float* wsf    = (float*)d_ws;
    float* h_tab  = wsf;                            // N*H
    float* d0     = h_tab + (size_t)N * H;          // N
    float* d1     = d0 + N;                         // N
    float* sumv   = d1 + N;                         // 128
    float* nbre   = sumv + 128;                     // 128*MAXD
    float* Mstat  = nbre + 128 * MAXD;              // 128*H
    float* dl_q   = Mstat + 128 * H;                // 128*MAXDIRTY
    float* dtv    = dl_q + 128 * MAXDIRTY;          // 128
    float* z_slot = dtv + 128;                      // 128*H
    float* h_slot = z_slot + 128 * H;               // 128*H
    int*   deg    = (int*)(h_slot + 128 * H);       // 128
    int*   dcnt   = deg + 128;                      // 128
    int*   nbri   = dcnt + 128;                     // 128*MAXD
    int*   dl_s   = nbri + 128 * MAXD;              // 128*MAXDIRTY
    int*   fu     = dl_s + 128 * MAXDIRTY;          // N
    int*   nodeofslot = fu + N;                     // 128
    int*   zdep   = nodeofslot + 128;               // 128
    int*   lastup = zdep + 128;                     // 128
    int*   hpub   = lastup + 128;                   // 128
    int*   consumed = hpub + 128;                   // 64
    unsigned long long* donebits = (unsigned long long*)(consumed + 64); // 1 (8B-aligned)

    float* out    = (float*)d_out;
    float* lamout = out;            // [64]
    float* svout  = out + NEV;      // [20]
    float* z_out  = out + NEV + SS; // [N*H]

    k_init<<<1, 256, 0, stream>>>(u, v, t, lastt, fu, nodeofslot, zdep, lastup,
                                  dtv, deg, dcnt, hpub, consumed, donebits);
    k_emb<<<N / RPB, 512, 0, stream>>>(emb, W_h, b_h, W_om, h_tab, z_out, d0, d1);
    k_nbr<<<128, 256, 0, stream>>>(u, v, A, S, deg, sumv, nbri, nbre);
    k_dm<<<128, 128, 0, stream>>>(deg, sumv, nbri, nbre, fu, h_tab, nodeofslot,
                                  Mstat, dcnt, dl_s, dl_q, hpub, consumed);
    k_ls<<<SS + 1, 64, 0, stream>>>(u, v, k, u_others, v_others, d0, d1, psi, b_om,
                                    lamout, svout);
    k_par<<<NEV, 256, 0, stream>>>(emb, W_S, W_R, W_t, W_h, b_h,
                                   deg, dcnt, dl_s, dl_q, Mstat, dtv,
                                   zdep, lastup, hpub, nodeofslot, consumed,
                                   z_slot, h_slot, donebits, z_out);
}

// Round 14
// 128.827 us; speedup vs baseline: 1.9275x; 1.1133x over previous
//
#include <hip/hip_runtime.h>
#include <math.h>

#define N 8192
#define H 128
#define NEV 64
#define SS 20
#define MAXD 512
#define MAXDIRTY 128
#define RPB 32
#define SPIN_GUARD (1 << 18)

// ---------------------------------------------------------------------------
// k_init: per-slot dependency metadata + consumed seeding from zdep.
// Zeroes hpub/consumed/donebits. (deg/dcnt now written by k_nbrdm.)
// ---------------------------------------------------------------------------
__global__ __launch_bounds__(256) void k_init(
    const int* __restrict__ u, const int* __restrict__ v,
    const float* __restrict__ t, const float* __restrict__ lastt,
    int* __restrict__ fu, int* __restrict__ nodeofslot,
    int* __restrict__ zdep, int* __restrict__ lastup,
    float* __restrict__ dtv, int* __restrict__ hpub, int* __restrict__ consumed,
    unsigned long long* __restrict__ donebits)
{
    __shared__ int fuL[N];       // 32 KB
    __shared__ int nodL[2 * NEV];
    const int tid = threadIdx.x;
    for (int i = tid; i < N; i += 256) fuL[i] = 0x7FFFFFFF;
    if (tid < 128) hpub[tid] = 0;
    if (tid < NEV) consumed[tid] = 0;
    if (tid == 0) donebits[0] = 0ull;
    if (tid < 2 * NEV) {
        const int e = tid >> 1, i = tid & 1;
        nodL[tid] = i ? u[e] : v[e];        // slot 2e -> v[e], 2e+1 -> u[e]
        nodeofslot[tid] = nodL[tid];
    }
    __syncthreads();
    if (tid < 2 * NEV) atomicMin(&fuL[nodL[tid]], tid);
    __syncthreads();
    for (int i = tid; i < N; i += 256) fu[i] = fuL[i];
    if (tid < 2 * NEV) {
        const int slot = tid, e = slot >> 1, i = slot & 1;
        const int node = nodL[slot];
        int zd = -1;
        for (int j = 2 * e - 1; j >= 0; --j)
            if (nodL[j] == node) { zd = j; break; }
        zdep[slot] = zd;
        if (zd >= 0) consumed[zd >> 1] = 1;   // z of event zd>>1 is consumed
        int lu = 1;
        for (int j = slot + 1; j < 2 * NEV; ++j)
            if (nodL[j] == node) { lu = 0; break; }
        lastup[slot] = lu;
        const int dtn = i ? v[e] : u[e];     // crossed: row v uses let[u], row u let[v]
        int pt = -1;
        for (int e2 = e - 1; e2 >= 0; --e2)
            if (u[e2] == dtn || v[e2] == dtn) { pt = e2; break; }
        const float lv = (pt >= 0) ? t[pt] : lastt[dtn];
        dtv[slot] = t[e] - lv;
    }
}

// ---------------------------------------------------------------------------
// k_emb: h_tab = emb @ W_h.T + b_h ; z_out = emb copy ; d0/d1 rate dots.
// [byte-identical to round 13]
// ---------------------------------------------------------------------------
__global__ __launch_bounds__(512) void k_emb(
    const float* __restrict__ emb, const float* __restrict__ W_h,
    const float* __restrict__ b_h, const float* __restrict__ W_om,
    float* __restrict__ h_tab, float* __restrict__ z_out,
    float* __restrict__ d0, float* __restrict__ d1)
{
    const int tid = threadIdx.x;
    const int c = tid & 127;
    const int s = tid >> 7;             // 0..3
    const int r0 = blockIdx.x * RPB;

    __shared__ __align__(16) float z4[4 * 128];
    __shared__ float pr[8 * 128];

    float whr[32];
#pragma unroll
    for (int i = 0; i < 32; ++i) whr[i] = W_h[c * H + s * 32 + i];
    const float bh_c = b_h[c];

    const int lane = tid & 63;
    const int wid = tid >> 6;
    const int kof = (wid >= 4) ? 256 : 0;
    const float wk_l = W_om[kof + lane]      + W_om[kof + 128 + lane];
    const float wk_h = W_om[kof + 64 + lane] + W_om[kof + 192 + lane];

    for (int b = 0; b < RPB / 4; ++b) {
        const int rbase = r0 + b * 4;
        __syncthreads();
        const float zv = emb[(size_t)rbase * H + tid];
        z4[tid] = zv;
        z_out[(size_t)rbase * H + tid] = zv;
        __syncthreads();

#pragma unroll
        for (int rr = 0; rr < 4; ++rr) {
            float a = 0.f;
#pragma unroll
            for (int i4 = 0; i4 < 8; ++i4) {
                const float4 zz = *(const float4*)&z4[rr * 128 + s * 32 + i4 * 4];
                a += zz.x * whr[i4 * 4] + zz.y * whr[i4 * 4 + 1] +
                     zz.z * whr[i4 * 4 + 2] + zz.w * whr[i4 * 4 + 3];
            }
            pr[(s * 4 + rr) * 128 + c] = a;
        }
        {
            const int rr = wid & 3;
            float val = z4[rr * 128 + lane] * wk_l + z4[rr * 128 + 64 + lane] * wk_h;
#pragma unroll
            for (int off = 32; off > 0; off >>= 1) val += __shfl_xor(val, off);
            if (lane == 0) {
                if (wid < 4) d0[rbase + rr] = val;
                else         d1[rbase + rr] = val;
            }
        }
        __syncthreads();
        {
            const int rr = s;
            const float h = pr[(0 * 4 + rr) * 128 + c] + pr[(1 * 4 + rr) * 128 + c] +
                            pr[(2 * 4 + rr) * 128 + c] + pr[(3 * 4 + rr) * 128 + c] + bh_c;
            h_tab[(size_t)(rbase + rr) * H + c] = h;
        }
    }
}

// ---------------------------------------------------------------------------
// k_nbrdm: merged neighbor-compaction + Mstat + dirty-list, one block per
// slot, all lists in LDS (no global nbri/nbre/sumv round-trip). Single role;
// inputs h_tab (k_emb) and fu/nodeofslot (k_init) are stream-ordered.
// ---------------------------------------------------------------------------
__global__ __launch_bounds__(256) void k_nbrdm(
    const int* __restrict__ u, const int* __restrict__ v,
    const float* __restrict__ A, const float* __restrict__ S,
    const int* __restrict__ fu, const float* __restrict__ h_tab,
    const int* __restrict__ nodeofslot,
    int* __restrict__ deg, float* __restrict__ Mstat,
    int* __restrict__ dcnt, int* __restrict__ dl_s, float* __restrict__ dl_q,
    int* __restrict__ hpub, int* __restrict__ consumed)
{
    __shared__ float rs[256];
    __shared__ int   nbrL_i[MAXD];
    __shared__ float nbrL_e[MAXD];
    __shared__ float redm[256];
    __shared__ int   nodL[2 * NEV];
    __shared__ int   dlL_s[MAXDIRTY];
    __shared__ float dlL_q[MAXDIRTY];
    __shared__ int   cntL, dcL;
    __shared__ float sumL;

    const int slot = blockIdx.x;
    const int e = slot >> 1, side = slot & 1;
    const int row = (side == 0) ? v[e] : u[e];
    const size_t base = (size_t)row * N;
    const int tid = threadIdx.x;

    if (tid == 0) { cntL = 0; dcL = 0; }
    if (tid < 2 * NEV) nodL[tid] = nodeofslot[tid];
    __syncthreads();

    // ---- phase 1: scan adjacency row, compact into LDS, sum exp(S) ----
    float lsum = 0.f;
    for (int j = tid; j < N; j += 256) {
        if (A[base + j] > 0.f) {
            const float ev = expf(S[base + j]);
            lsum += ev;
            const int p = atomicAdd(&cntL, 1);
            if (p < MAXD) { nbrL_i[p] = j; nbrL_e[p] = ev; }
        }
    }
    rs[tid] = lsum;
    __syncthreads();
    for (int off = 128; off > 0; off >>= 1) {
        if (tid < off) rs[tid] += rs[tid + off];
        __syncthreads();
    }
    if (tid == 0) { sumL = rs[0]; deg[slot] = cntL; }
    __syncthreads();

    const int d = min(cntL, MAXD);
    const float rinv = 1.f / (sumL + 1e-7f);

    // ---- phase 2: Mstat over static (fu[j] >= 2e) neighbors ----
    {
        const int c = tid & 127, half = tid >> 7;
        float m = -INFINITY;
        for (int j0 = half; j0 < d; j0 += 2) {
            const int j = nbrL_i[j0];
            if (fu[j] >= 2 * e)
                m = fmaxf(m, nbrL_e[j0] * rinv * h_tab[(size_t)j * H + c]);
        }
        redm[tid] = m;
        __syncthreads();
        if (tid < 128) Mstat[slot * H + c] = fmaxf(redm[c], redm[128 + c]);
    }

    // ---- phase 3: dirty list (latest-updater dep slots) ----
    for (int j0 = tid; j0 < d; j0 += 256) {
        const int j = nbrL_i[j0];
        if (fu[j] < 2 * e) {
            int dep = -1;                              // latest updater < 2e
            for (int s2 = 2 * e - 1; s2 >= 0; --s2)
                if (nodL[s2] == j) { dep = s2; break; }
            const int p = atomicAdd(&dcL, 1);
            if (p < MAXDIRTY) { dlL_s[p] = dep; dlL_q[p] = nbrL_e[j0] * rinv; }
            hpub[dep] = 1;
            consumed[dep >> 1] = 1;
        }
    }
    __syncthreads();
    if (tid == 0) dcnt[slot] = dcL;
    const int nd = min(dcL, MAXDIRTY);
    for (int p = tid; p < nd; p += 256) {
        dl_s[slot * MAXDIRTY + p] = dlL_s[p];
        dl_q[slot * MAXDIRTY + p] = dlL_q[p];
    }
}

// ---------------------------------------------------------------------------
// k_ls: lam (block 0) + survival (blocks 1..SS). [byte-identical to round 13]
// ---------------------------------------------------------------------------
__global__ __launch_bounds__(64) void k_ls(
    const int* __restrict__ u, const int* __restrict__ v, const int* __restrict__ kk,
    const int* __restrict__ u_o, const int* __restrict__ v_o,
    const float* __restrict__ d0, const float* __restrict__ d1,
    const float* __restrict__ psi, const float* __restrict__ b_om,
    float* __restrict__ lamout, float* __restrict__ svout)
{
    const int b = threadIdx.x;
    if (blockIdx.x == 0) {
        if (b < NEV) {
            const int kv = kk[b];
            const float* dk = kv ? d1 : d0;
            const float g = 0.5f * (dk[u[b]] + dk[v[b]]) + b_om[kv];
            const float ps = psi[kv];
            const float x = fminf(75.f, fmaxf(-75.f, g / ps));
            lamout[b] = ps * log1pf(expf(x));
        }
    } else {
        const int s = blockIdx.x - 1;
        const float p0 = psi[0], p1 = psi[1], bo0 = b_om[0], bo1 = b_om[1];
        const int vo = v_o[b * SS + s], uo = u_o[b * SS + s];
        float g, x;
        g = 0.5f * (d0[u[b]] + d0[vo]) + bo0; x = fminf(75.f, fmaxf(-75.f, g / p0));
        const float ru0 = p0 * log1pf(expf(x));
        g = 0.5f * (d1[u[b]] + d1[vo]) + bo1; x = fminf(75.f, fmaxf(-75.f, g / p1));
        const float ru1 = p1 * log1pf(expf(x));
        g = 0.5f * (d1[v[b]] + d1[uo]) + bo1; x = fminf(75.f, fmaxf(-75.f, g / p1));
        const float rv1 = p1 * log1pf(expf(x));
        float val = 2.f * (ru0 + ru1) + rv1;
#pragma unroll
        for (int off = 32; off > 0; off >>= 1) val += __shfl_xor(val, off);
        if (b == 0) svout[s] = val / (float)SS;
    }
}

// ---------------------------------------------------------------------------
// k_par: one block per event. [byte-identical to round 13 — passed]
// ---------------------------------------------------------------------------
__global__ __launch_bounds__(256) void k_par(
    const float* __restrict__ emb,
    const float* __restrict__ W_S, const float* __restrict__ W_R,
    const float* __restrict__ W_t, const float* __restrict__ W_h,
    const float* __restrict__ b_h,
    const int* __restrict__ deg, const int* __restrict__ dcnt,
    const int* __restrict__ dl_s, const float* __restrict__ dl_q,
    const float* __restrict__ Mstat, const float* __restrict__ dtv,
    const int* __restrict__ zdep, const int* __restrict__ lastup,
    const int* __restrict__ hpub, const int* __restrict__ nodeofslot,
    const int* __restrict__ consumed,
    float* __restrict__ z_slot, float* __restrict__ h_slot,
    unsigned long long* __restrict__ donebits,
    float* __restrict__ z_out)
{
    const int e = blockIdx.x;
    const int tid = threadIdx.x;
    const int r = tid >> 7;             // wave-uniform (waves 0-1: r=0, 2-3: r=1)
    const int c = tid & 127;
    const int slot = 2 * e + r;

    __shared__ __align__(16) float hs_s[2][128];
    __shared__ __align__(16) float zz_s[2][128];
    __shared__ __align__(16) float zn_s[2][128];
    __shared__ unsigned long long need_s;

    if (tid == 0) {
        unsigned long long need = 0ull;
        for (int rr = 0; rr < 2; ++rr) {
            const int sl = 2 * e + rr;
            const int zd = zdep[sl];
            if (zd >= 0) need |= 1ull << (zd >> 1);
            const int dn = min(dcnt[sl], MAXDIRTY);
            for (int p = 0; p < dn; ++p)
                need |= 1ull << (dl_s[sl * MAXDIRTY + p] >> 1);
        }
        need_s = need;
        if (need) {
            int guard = 0;
            while ((__hip_atomic_load(donebits, __ATOMIC_ACQUIRE,
                                      __HIP_MEMORY_SCOPE_AGENT) & need) != need) {
                __builtin_amdgcn_s_sleep(2);
                if (++guard > SPIN_GUARD) break;       // safety valve
            }
        }
    }
    __syncthreads();
    if (need_s) {
        unsigned long long db = __hip_atomic_load(donebits, __ATOMIC_ACQUIRE,
                                                  __HIP_MEMORY_SCOPE_AGENT);
        (void)db;
    }

    // ---- Phase A ----
    {
        float m = Mstat[slot * H + c];
        const int dn = min(dcnt[slot], MAXDIRTY);
        for (int p = 0; p < dn; ++p) {
            const int ds = dl_s[slot * MAXDIRTY + p];
            const float q = dl_q[slot * MAXDIRTY + p];
            m = fmaxf(m, q * h_slot[ds * H + c]);
        }
        hs_s[r][c] = (deg[slot] > 0) ? 1.f / (1.f + __expf(-m)) : 0.f;
        const int zd = zdep[slot];
        zz_s[r][c] = (zd >= 0) ? z_slot[zd * H + c]
                               : emb[(size_t)nodeofslot[slot] * H + c];
    }
    __syncthreads();

    // ---- Phase B ----
    float g = 0.f;
    {
        const float4* ws4 = (const float4*)(W_S + (size_t)c * H);
        const float4* wr4 = (const float4*)(W_R + (size_t)c * H);
#pragma unroll
        for (int i = 0; i < 32; ++i) {
            const float4 a = ws4[i];
            const float4 b = wr4[i];
            const float4 hh = *(const float4*)&hs_s[r][4 * i];
            const float4 zz = *(const float4*)&zz_s[r][4 * i];
            g += hh.x * a.x + hh.y * a.y + hh.z * a.z + hh.w * a.w +
                 zz.x * b.x + zz.y * b.y + zz.z * b.z + zz.w * b.w;
        }
    }
    g += dtv[slot] * W_t[c];
    const float zv = 1.f / (1.f + __expf(-g));
    zn_s[r][c] = zv;
    z_slot[slot * H + c] = zv;
    if (lastup[slot])
        z_out[(size_t)nodeofslot[slot] * H + c] = zv;
    __syncthreads();

    // ---- Phase C ----
    if (hpub[slot]) {
        float h = 0.f;
        const float4* wh4 = (const float4*)(W_h + (size_t)c * H);
#pragma unroll
        for (int i = 0; i < 32; ++i) {
            const float4 a = wh4[i];
            const float4 zz = *(const float4*)&zn_s[r][4 * i];
            h += zz.x * a.x + zz.y * a.y + zz.z * a.z + zz.w * a.w;
        }
        h_slot[slot * H + c] = h + b_h[c];
    }

    __syncthreads();
    if (tid == 0 && consumed[e]) {
        __threadfence();
        __hip_atomic_fetch_or(donebits, 1ull << e, __ATOMIC_RELEASE,
                              __HIP_MEMORY_SCOPE_AGENT);
    }
}

// ---------------------------------------------------------------------------
extern "C" void kernel_launch(void* const* d_in, const int* in_sizes, int n_in,
                              void* d_out, int out_size, void* d_ws, size_t ws_size,
                              hipStream_t stream)
{
    const int*   u        = (const int*)d_in[0];
    const int*   v        = (const int*)d_in[1];
    const float* t        = (const float*)d_in[2];
    const int*   k        = (const int*)d_in[3];
    const int*   u_others = (const int*)d_in[4];
    const int*   v_others = (const int*)d_in[5];
    const float* A        = (const float*)d_in[6];
    const float* S        = (const float*)d_in[7];
    const float* emb      = (const float*)d_in[8];
    const float* lastt    = (const float*)d_in[9];
    const float* W_S      = (const float*)d_in[10];
    const float* W_R      = (const float*)d_in[11];
    const float* W_t      = (const float*)d_in[12];
    const float* W_h      = (const float*)d_in[13];
    const float* b_h      = (const float*)d_in[14];
    const float* psi      = (const float*)d_in[15];
    const float* W_om     = (const float*)d_in[16];
    const float* b_om     = (const float*)d_in[17];
    (void)in_sizes; (void)n_in; (void)out_size; (void)ws_size;

    float* wsf    = (float*)d_ws;
    float* h_tab  = wsf;                            // N*H
    float* d0     = h_tab + (size_t)N * H;          // N
    float* d1     = d0 + N;                         // N
    float* Mstat  = d1 + N;                         // 128*H
    float* dl_q   = Mstat + 128 * H;                // 128*MAXDIRTY
    float* dtv    = dl_q + 128 * MAXDIRTY;          // 128
    float* z_slot = dtv + 128;                      // 128*H
    float* h_slot = z_slot + 128 * H;               // 128*H
    int*   deg    = (int*)(h_slot + 128 * H);       // 128
    int*   dcnt   = deg + 128;                      // 128
    int*   dl_s   = dcnt + 128;                     // 128*MAXDIRTY
    int*   fu     = dl_s + 128 * MAXDIRTY;          // N
    int*   nodeofslot = fu + N;                     // 128
    int*   zdep   = nodeofslot + 128;               // 128
    int*   lastup = zdep + 128;                     // 128
    int*   hpub   = lastup + 128;                   // 128
    int*   consumed = hpub + 128;                   // 64
    unsigned long long* donebits = (unsigned long long*)(consumed + 64); // 8B-aligned

    float* out    = (float*)d_out;
    float* lamout = out;            // [64]
    float* svout  = out + NEV;      // [20]
    float* z_out  = out + NEV + SS; // [N*H]

    k_init<<<1, 256, 0, stream>>>(u, v, t, lastt, fu, nodeofslot, zdep, lastup,
                                  dtv, hpub, consumed, donebits);
    k_emb<<<N / RPB, 512, 0, stream>>>(emb, W_h, b_h, W_om, h_tab, z_out, d0, d1);
    k_nbrdm<<<128, 256, 0, stream>>>(u, v, A, S, fu, h_tab, nodeofslot,
                                     deg, Mstat, dcnt, dl_s, dl_q, hpub, consumed);
    k_ls<<<SS + 1, 64, 0, stream>>>(u, v, k, u_others, v_others, d0, d1, psi, b_om,
                                    lamout, svout);
    k_par<<<NEV, 256, 0, stream>>>(emb, W_S, W_R, W_t, W_h, b_h,
                                   deg, dcnt, dl_s, dl_q, Mstat, dtv,
                                   zdep, lastup, hpub, nodeofslot, consumed,
                                   z_slot, h_slot, donebits, z_out);
}

// Round 15
// 114.378 us; speedup vs baseline: 2.1710x; 1.1263x over previous
//
#include <hip/hip_runtime.h>
#include <math.h>

#define N 8192
#define H 128
#define NEV 64
#define SS 20
#define MAXD 512
#define MAXDIRTY 128
#define RPB 32
#define SPIN_GUARD (1 << 18)

// ---------------------------------------------------------------------------
// k_emb: h_tab = emb @ W_h.T + b_h ; z_out = emb copy ; d0/d1 rate dots.
// [byte-identical to rounds 13/14 — passed repeatedly]
// ---------------------------------------------------------------------------
__global__ __launch_bounds__(512) void k_emb(
    const float* __restrict__ emb, const float* __restrict__ W_h,
    const float* __restrict__ b_h, const float* __restrict__ W_om,
    float* __restrict__ h_tab, float* __restrict__ z_out,
    float* __restrict__ d0, float* __restrict__ d1)
{
    const int tid = threadIdx.x;
    const int c = tid & 127;
    const int s = tid >> 7;             // 0..3
    const int r0 = blockIdx.x * RPB;

    __shared__ __align__(16) float z4[4 * 128];
    __shared__ float pr[8 * 128];

    float whr[32];
#pragma unroll
    for (int i = 0; i < 32; ++i) whr[i] = W_h[c * H + s * 32 + i];
    const float bh_c = b_h[c];

    const int lane = tid & 63;
    const int wid = tid >> 6;
    const int kof = (wid >= 4) ? 256 : 0;
    const float wk_l = W_om[kof + lane]      + W_om[kof + 128 + lane];
    const float wk_h = W_om[kof + 64 + lane] + W_om[kof + 192 + lane];

    for (int b = 0; b < RPB / 4; ++b) {
        const int rbase = r0 + b * 4;
        __syncthreads();
        const float zv = emb[(size_t)rbase * H + tid];
        z4[tid] = zv;
        z_out[(size_t)rbase * H + tid] = zv;
        __syncthreads();

#pragma unroll
        for (int rr = 0; rr < 4; ++rr) {
            float a = 0.f;
#pragma unroll
            for (int i4 = 0; i4 < 8; ++i4) {
                const float4 zz = *(const float4*)&z4[rr * 128 + s * 32 + i4 * 4];
                a += zz.x * whr[i4 * 4] + zz.y * whr[i4 * 4 + 1] +
                     zz.z * whr[i4 * 4 + 2] + zz.w * whr[i4 * 4 + 3];
            }
            pr[(s * 4 + rr) * 128 + c] = a;
        }
        {
            const int rr = wid & 3;
            float val = z4[rr * 128 + lane] * wk_l + z4[rr * 128 + 64 + lane] * wk_h;
#pragma unroll
            for (int off = 32; off > 0; off >>= 1) val += __shfl_xor(val, off);
            if (lane == 0) {
                if (wid < 4) d0[rbase + rr] = val;
                else         d1[rbase + rr] = val;
            }
        }
        __syncthreads();
        {
            const int rr = s;
            const float h = pr[(0 * 4 + rr) * 128 + c] + pr[(1 * 4 + rr) * 128 + c] +
                            pr[(2 * 4 + rr) * 128 + c] + pr[(3 * 4 + rr) * 128 + c] + bh_c;
            h_tab[(size_t)(rbase + rr) * H + c] = h;
        }
    }
}

// ---------------------------------------------------------------------------
// k_nbrdm: merged neighbor-compaction + Mstat + dirty-list, one block per
// slot, all lists in LDS. NEW vs r14: per-neighbor latest-updater dep
// (flagL) computed from the event list in LDS (replaces global fu),
// S read only where A>0, block 0 zeroes donebits (consumed by k_par next
// dispatch, stream-ordered). hpub/consumed dropped (k_par now unconditional).
// ---------------------------------------------------------------------------
__global__ __launch_bounds__(256) void k_nbrdm(
    const int* __restrict__ u, const int* __restrict__ v,
    const float* __restrict__ A, const float* __restrict__ S,
    const float* __restrict__ h_tab,
    int* __restrict__ deg, float* __restrict__ Mstat,
    int* __restrict__ dcnt, int* __restrict__ dl_s, float* __restrict__ dl_q,
    unsigned long long* __restrict__ donebits)
{
    __shared__ float rs[256];
    __shared__ int   nbrL_i[MAXD];
    __shared__ float nbrL_e[MAXD];
    __shared__ int   flagL[MAXD];
    __shared__ float redm[256];
    __shared__ int   nodL[2 * NEV];
    __shared__ int   dlL_s[MAXDIRTY];
    __shared__ float dlL_q[MAXDIRTY];
    __shared__ int   cntL, dcL;
    __shared__ float sumL;

    const int slot = blockIdx.x;
    const int e = slot >> 1, side = slot & 1;
    const int row = (side == 0) ? v[e] : u[e];
    const size_t base = (size_t)row * N;
    const int tid = threadIdx.x;

    if (blockIdx.x == 0 && tid == 0) donebits[0] = 0ull;   // for k_par (next dispatch)
    if (tid == 0) { cntL = 0; dcL = 0; }
    if (tid < 2 * NEV) nodL[tid] = (tid & 1) ? u[tid >> 1] : v[tid >> 1];
    __syncthreads();

    // ---- phase 1: scan adjacency row, compact into LDS, sum exp(S) ----
    float lsum = 0.f;
    for (int j = tid; j < N; j += 256) {
        if (A[base + j] > 0.f) {
            const float ev = expf(S[base + j]);
            lsum += ev;
            const int p = atomicAdd(&cntL, 1);
            if (p < MAXD) { nbrL_i[p] = j; nbrL_e[p] = ev; }
        }
    }
    rs[tid] = lsum;
    __syncthreads();
    for (int off = 128; off > 0; off >>= 1) {
        if (tid < off) rs[tid] += rs[tid + off];
        __syncthreads();
    }
    if (tid == 0) { sumL = rs[0]; deg[slot] = cntL; }
    __syncthreads();

    const int d = min(cntL, MAXD);
    const float rinv = 1.f / (sumL + 1e-7f);

    // ---- phase 1.5: per-neighbor latest-updater slot strictly before e ----
    for (int j0 = tid; j0 < d; j0 += 256) {
        const int j = nbrL_i[j0];
        int dep = -1;
        for (int s2 = 2 * e - 1; s2 >= 0; --s2)
            if (nodL[s2] == j) { dep = s2; break; }
        flagL[j0] = dep;                      // <0: static; >=0: dirty dep slot
    }
    __syncthreads();

    // ---- phase 2: Mstat over static neighbors ----
    {
        const int c = tid & 127, half = tid >> 7;
        float m = -INFINITY;
        for (int j0 = half; j0 < d; j0 += 2) {
            if (flagL[j0] < 0)
                m = fmaxf(m, nbrL_e[j0] * rinv * h_tab[(size_t)nbrL_i[j0] * H + c]);
        }
        redm[tid] = m;
        __syncthreads();
        if (tid < 128) Mstat[slot * H + c] = fmaxf(redm[c], redm[128 + c]);
    }

    // ---- phase 3: dirty list (latest-updater dep slots) ----
    for (int j0 = tid; j0 < d; j0 += 256) {
        const int dep = flagL[j0];
        if (dep >= 0) {
            const int p = atomicAdd(&dcL, 1);
            if (p < MAXDIRTY) { dlL_s[p] = dep; dlL_q[p] = nbrL_e[j0] * rinv; }
        }
    }
    __syncthreads();
    if (tid == 0) dcnt[slot] = dcL;
    const int nd = min(dcL, MAXDIRTY);
    for (int p = tid; p < nd; p += 256) {
        dl_s[slot * MAXDIRTY + p] = dlL_s[p];
        dl_q[slot * MAXDIRTY + p] = dlL_q[p];
    }
}

// ---------------------------------------------------------------------------
// k_ls: lam (block 0) + survival (blocks 1..SS). [byte-identical to r13/r14]
// ---------------------------------------------------------------------------
__global__ __launch_bounds__(64) void k_ls(
    const int* __restrict__ u, const int* __restrict__ v, const int* __restrict__ kk,
    const int* __restrict__ u_o, const int* __restrict__ v_o,
    const float* __restrict__ d0, const float* __restrict__ d1,
    const float* __restrict__ psi, const float* __restrict__ b_om,
    float* __restrict__ lamout, float* __restrict__ svout)
{
    const int b = threadIdx.x;
    if (blockIdx.x == 0) {
        if (b < NEV) {
            const int kv = kk[b];
            const float* dk = kv ? d1 : d0;
            const float g = 0.5f * (dk[u[b]] + dk[v[b]]) + b_om[kv];
            const float ps = psi[kv];
            const float x = fminf(75.f, fmaxf(-75.f, g / ps));
            lamout[b] = ps * log1pf(expf(x));
        }
    } else {
        const int s = blockIdx.x - 1;
        const float p0 = psi[0], p1 = psi[1], bo0 = b_om[0], bo1 = b_om[1];
        const int vo = v_o[b * SS + s], uo = u_o[b * SS + s];
        float g, x;
        g = 0.5f * (d0[u[b]] + d0[vo]) + bo0; x = fminf(75.f, fmaxf(-75.f, g / p0));
        const float ru0 = p0 * log1pf(expf(x));
        g = 0.5f * (d1[u[b]] + d1[vo]) + bo1; x = fminf(75.f, fmaxf(-75.f, g / p1));
        const float ru1 = p1 * log1pf(expf(x));
        g = 0.5f * (d1[v[b]] + d1[uo]) + bo1; x = fminf(75.f, fmaxf(-75.f, g / p1));
        const float rv1 = p1 * log1pf(expf(x));
        float val = 2.f * (ru0 + ru1) + rv1;
#pragma unroll
        for (int off = 32; off > 0; off >>= 1) val += __shfl_xor(val, off);
        if (b == 0) svout[s] = val / (float)SS;
    }
}

// ---------------------------------------------------------------------------
// k_par: one block per event (r9/r13-proven protocol). NEW vs r14: per-slot
// metadata (zdep/lastup/dtv/node) computed locally from the event list in
// LDS (k_init eliminated); phase C and release unconditional (as r9).
// ---------------------------------------------------------------------------
__global__ __launch_bounds__(256) void k_par(
    const int* __restrict__ u, const int* __restrict__ v,
    const float* __restrict__ t, const float* __restrict__ lastt,
    const float* __restrict__ emb,
    const float* __restrict__ W_S, const float* __restrict__ W_R,
    const float* __restrict__ W_t, const float* __restrict__ W_h,
    const float* __restrict__ b_h,
    const int* __restrict__ deg, const int* __restrict__ dcnt,
    const int* __restrict__ dl_s, const float* __restrict__ dl_q,
    const float* __restrict__ Mstat,
    float* __restrict__ z_slot, float* __restrict__ h_slot,
    unsigned long long* __restrict__ donebits,
    float* __restrict__ z_out)
{
    const int e = blockIdx.x;
    const int tid = threadIdx.x;
    const int r = tid >> 7;             // wave-uniform (waves 0-1: r=0, 2-3: r=1)
    const int c = tid & 127;
    const int slot = 2 * e + r;

    __shared__ __align__(16) float hs_s[2][128];
    __shared__ __align__(16) float zz_s[2][128];
    __shared__ __align__(16) float zn_s[2][128];
    __shared__ int   uL[NEV], vL[NEV];
    __shared__ int   zdepL[2], lastupL[2], nodeL[2];
    __shared__ float dtvL[2];
    __shared__ unsigned long long need_s;

    if (tid < NEV)                 uL[tid] = u[tid];
    else if (tid < 2 * NEV)        vL[tid - NEV] = v[tid - NEV];
    __syncthreads();

    // ---- per-slot metadata from the event list (replaces k_init) ----
    if (tid < 2) {
        const int sl = 2 * e + tid;
        const int node = tid ? uL[e] : vL[e];    // slot 2e -> v[e], 2e+1 -> u[e]
        nodeL[tid] = node;
        int zd = -1;
        for (int j = 2 * e - 1; j >= 0; --j) {
            const int nj = (j & 1) ? uL[j >> 1] : vL[j >> 1];
            if (nj == node) { zd = j; break; }
        }
        zdepL[tid] = zd;
        int lu = 1;
        for (int j = sl + 1; j < 2 * NEV; ++j) {
            const int nj = (j & 1) ? uL[j >> 1] : vL[j >> 1];
            if (nj == node) { lu = 0; break; }
        }
        lastupL[tid] = lu;
        const int dtn = tid ? vL[e] : uL[e];     // crossed: row v uses let[u], row u let[v]
        int pt = -1;
        for (int e2 = e - 1; e2 >= 0; --e2)
            if (uL[e2] == dtn || vL[e2] == dtn) { pt = e2; break; }
        const float lv = (pt >= 0) ? t[pt] : lastt[dtn];
        dtvL[tid] = t[e] - lv;
    }
    __syncthreads();

    // ---- build need-mask and spin (thread 0), then per-thread acquire ----
    if (tid == 0) {
        unsigned long long need = 0ull;
        for (int rr = 0; rr < 2; ++rr) {
            const int zd = zdepL[rr];
            if (zd >= 0) need |= 1ull << (zd >> 1);
            const int sl = 2 * e + rr;
            const int dn = min(dcnt[sl], MAXDIRTY);
            for (int p = 0; p < dn; ++p)
                need |= 1ull << (dl_s[sl * MAXDIRTY + p] >> 1);
        }
        need_s = need;
        if (need) {
            int guard = 0;
            while ((__hip_atomic_load(donebits, __ATOMIC_ACQUIRE,
                                      __HIP_MEMORY_SCOPE_AGENT) & need) != need) {
                __builtin_amdgcn_s_sleep(2);
                if (++guard > SPIN_GUARD) break;       // safety valve
            }
        }
    }
    __syncthreads();
    if (need_s) {   // per-thread acquire: invalidate stale cache lines on this CU
        unsigned long long db = __hip_atomic_load(donebits, __ATOMIC_ACQUIRE,
                                                  __HIP_MEMORY_SCOPE_AGENT);
        (void)db;
    }

    // ---- Phase A: hs (Mstat static max + dirty via h_slot) and z (versioned) ----
    {
        float m = Mstat[slot * H + c];
        const int dn = min(dcnt[slot], MAXDIRTY);
        for (int p = 0; p < dn; ++p) {
            const int ds = dl_s[slot * MAXDIRTY + p];
            const float q = dl_q[slot * MAXDIRTY + p];
            m = fmaxf(m, q * h_slot[ds * H + c]);
        }
        hs_s[r][c] = (deg[slot] > 0) ? 1.f / (1.f + __expf(-m)) : 0.f;
        const int zd = zdepL[r];
        zz_s[r][c] = (zd >= 0) ? z_slot[zd * H + c]
                               : emb[(size_t)nodeL[r] * H + c];
    }
    __syncthreads();

    // ---- Phase B: g = hs.W_S[c] + z.W_R[c] + dt*W_t[c]; sigmoid ----
    float g = 0.f;
    {
        const float4* ws4 = (const float4*)(W_S + (size_t)c * H);
        const float4* wr4 = (const float4*)(W_R + (size_t)c * H);
#pragma unroll
        for (int i = 0; i < 32; ++i) {
            const float4 a = ws4[i];
            const float4 b = wr4[i];
            const float4 hh = *(const float4*)&hs_s[r][4 * i];   // LDS broadcast
            const float4 zz = *(const float4*)&zz_s[r][4 * i];
            g += hh.x * a.x + hh.y * a.y + hh.z * a.z + hh.w * a.w +
                 zz.x * b.x + zz.y * b.y + zz.z * b.z + zz.w * b.w;
        }
    }
    g += dtvL[r] * W_t[c];
    const float zv = 1.f / (1.f + __expf(-g));
    zn_s[r][c] = zv;
    z_slot[slot * H + c] = zv;                      // versioned publish (z)
    if (lastupL[r])                                 // final updater writes output
        z_out[(size_t)nodeL[r] * H + c] = zv;
    __syncthreads();                                // zn_s ready for phase C

    // ---- Phase C: publish h_slot[slot] (unconditional, as r9) ----
    {
        float h = 0.f;
        const float4* wh4 = (const float4*)(W_h + (size_t)c * H);
#pragma unroll
        for (int i = 0; i < 32; ++i) {
            const float4 a = wh4[i];
            const float4 zz = *(const float4*)&zn_s[r][4 * i];
            h += zz.x * a.x + zz.y * a.y + zz.z * a.z + zz.w * a.w;
        }
        h_slot[slot * H + c] = h + b_h[c];
    }

    // ---- release (unconditional, as r9) ----
    __syncthreads();
    if (tid == 0) {
        __threadfence();                            // agent-scope write visibility
        __hip_atomic_fetch_or(donebits, 1ull << e, __ATOMIC_RELEASE,
                              __HIP_MEMORY_SCOPE_AGENT);
    }
}

// ---------------------------------------------------------------------------
extern "C" void kernel_launch(void* const* d_in, const int* in_sizes, int n_in,
                              void* d_out, int out_size, void* d_ws, size_t ws_size,
                              hipStream_t stream)
{
    const int*   u        = (const int*)d_in[0];
    const int*   v        = (const int*)d_in[1];
    const float* t        = (const float*)d_in[2];
    const int*   k        = (const int*)d_in[3];
    const int*   u_others = (const int*)d_in[4];
    const int*   v_others = (const int*)d_in[5];
    const float* A        = (const float*)d_in[6];
    const float* S        = (const float*)d_in[7];
    const float* emb      = (const float*)d_in[8];
    const float* lastt    = (const float*)d_in[9];
    const float* W_S      = (const float*)d_in[10];
    const float* W_R      = (const float*)d_in[11];
    const float* W_t      = (const float*)d_in[12];
    const float* W_h      = (const float*)d_in[13];
    const float* b_h      = (const float*)d_in[14];
    const float* psi      = (const float*)d_in[15];
    const float* W_om     = (const float*)d_in[16];
    const float* b_om     = (const float*)d_in[17];
    (void)in_sizes; (void)n_in; (void)out_size; (void)ws_size;

    float* wsf    = (float*)d_ws;
    float* h_tab  = wsf;                            // N*H
    float* d0     = h_tab + (size_t)N * H;          // N
    float* d1     = d0 + N;                         // N
    float* Mstat  = d1 + N;                         // 128*H
    float* dl_q   = Mstat + 128 * H;                // 128*MAXDIRTY
    float* z_slot = dl_q + 128 * MAXDIRTY;          // 128*H
    float* h_slot = z_slot + 128 * H;               // 128*H
    int*   deg    = (int*)(h_slot + 128 * H);       // 128
    int*   dcnt   = deg + 128;                      // 128
    int*   dl_s   = dcnt + 128;                     // 128*MAXDIRTY
    unsigned long long* donebits = (unsigned long long*)(dl_s + 128 * MAXDIRTY);

    float* out    = (float*)d_out;
    float* lamout = out;            // [64]
    float* svout  = out + NEV;      // [20]
    float* z_out  = out + NEV + SS; // [N*H]

    k_emb<<<N / RPB, 512, 0, stream>>>(emb, W_h, b_h, W_om, h_tab, z_out, d0, d1);
    k_nbrdm<<<128, 256, 0, stream>>>(u, v, A, S, h_tab,
                                     deg, Mstat, dcnt, dl_s, dl_q, donebits);
    k_ls<<<SS + 1, 64, 0, stream>>>(u, v, k, u_others, v_others, d0, d1, psi, b_om,
                                    lamout, svout);
    k_par<<<NEV, 256, 0, stream>>>(u, v, t, lastt, emb, W_S, W_R, W_t, W_h, b_h,
                                   deg, dcnt, dl_s, dl_q, Mstat,
                                   z_slot, h_slot, donebits, z_out);
}

// Round 16
// 112.271 us; speedup vs baseline: 2.2117x; 1.0188x over previous
//
#include <hip/hip_runtime.h>
#include <math.h>

#define N 8192
#define H 128
#define NEV 64
#define SS 20
#define MAXD 512
#define MAXDIRTY 128
#define RPB 32
#define SPIN_GUARD (1 << 18)

// ---------------------------------------------------------------------------
// k_emb: h_tab = emb @ W_h.T + b_h ; z_out = emb copy ; d0/d1 rate dots.
// [byte-identical to rounds 13/14/15 — passed repeatedly; STANDALONE by the
// producer-side curse rule (r5/r10 failures both had emb inside a multi-role
// kernel)]
// ---------------------------------------------------------------------------
__global__ __launch_bounds__(512) void k_emb(
    const float* __restrict__ emb, const float* __restrict__ W_h,
    const float* __restrict__ b_h, const float* __restrict__ W_om,
    float* __restrict__ h_tab, float* __restrict__ z_out,
    float* __restrict__ d0, float* __restrict__ d1)
{
    const int tid = threadIdx.x;
    const int c = tid & 127;
    const int s = tid >> 7;             // 0..3
    const int r0 = blockIdx.x * RPB;

    __shared__ __align__(16) float z4[4 * 128];
    __shared__ float pr[8 * 128];

    float whr[32];
#pragma unroll
    for (int i = 0; i < 32; ++i) whr[i] = W_h[c * H + s * 32 + i];
    const float bh_c = b_h[c];

    const int lane = tid & 63;
    const int wid = tid >> 6;
    const int kof = (wid >= 4) ? 256 : 0;
    const float wk_l = W_om[kof + lane]      + W_om[kof + 128 + lane];
    const float wk_h = W_om[kof + 64 + lane] + W_om[kof + 192 + lane];

    for (int b = 0; b < RPB / 4; ++b) {
        const int rbase = r0 + b * 4;
        __syncthreads();
        const float zv = emb[(size_t)rbase * H + tid];
        z4[tid] = zv;
        z_out[(size_t)rbase * H + tid] = zv;
        __syncthreads();

#pragma unroll
        for (int rr = 0; rr < 4; ++rr) {
            float a = 0.f;
#pragma unroll
            for (int i4 = 0; i4 < 8; ++i4) {
                const float4 zz = *(const float4*)&z4[rr * 128 + s * 32 + i4 * 4];
                a += zz.x * whr[i4 * 4] + zz.y * whr[i4 * 4 + 1] +
                     zz.z * whr[i4 * 4 + 2] + zz.w * whr[i4 * 4 + 3];
            }
            pr[(s * 4 + rr) * 128 + c] = a;
        }
        {
            const int rr = wid & 3;
            float val = z4[rr * 128 + lane] * wk_l + z4[rr * 128 + 64 + lane] * wk_h;
#pragma unroll
            for (int off = 32; off > 0; off >>= 1) val += __shfl_xor(val, off);
            if (lane == 0) {
                if (wid < 4) d0[rbase + rr] = val;
                else         d1[rbase + rr] = val;
            }
        }
        __syncthreads();
        {
            const int rr = s;
            const float h = pr[(0 * 4 + rr) * 128 + c] + pr[(1 * 4 + rr) * 128 + c] +
                            pr[(2 * 4 + rr) * 128 + c] + pr[(3 * 4 + rr) * 128 + c] + bh_c;
            h_tab[(size_t)(rbase + rr) * H + c] = h;
        }
    }
}

// ---------------------------------------------------------------------------
// k_nbrdm: merged neighbor-compaction + Mstat + dirty-list, one block per
// slot, all lists in LDS. [byte-identical to round 15 — passed]
// ---------------------------------------------------------------------------
__global__ __launch_bounds__(256) void k_nbrdm(
    const int* __restrict__ u, const int* __restrict__ v,
    const float* __restrict__ A, const float* __restrict__ S,
    const float* __restrict__ h_tab,
    int* __restrict__ deg, float* __restrict__ Mstat,
    int* __restrict__ dcnt, int* __restrict__ dl_s, float* __restrict__ dl_q,
    unsigned long long* __restrict__ donebits)
{
    __shared__ float rs[256];
    __shared__ int   nbrL_i[MAXD];
    __shared__ float nbrL_e[MAXD];
    __shared__ int   flagL[MAXD];
    __shared__ float redm[256];
    __shared__ int   nodL[2 * NEV];
    __shared__ int   dlL_s[MAXDIRTY];
    __shared__ float dlL_q[MAXDIRTY];
    __shared__ int   cntL, dcL;
    __shared__ float sumL;

    const int slot = blockIdx.x;
    const int e = slot >> 1, side = slot & 1;
    const int row = (side == 0) ? v[e] : u[e];
    const size_t base = (size_t)row * N;
    const int tid = threadIdx.x;

    if (blockIdx.x == 0 && tid == 0) donebits[0] = 0ull;   // for k_parls (next dispatch)
    if (tid == 0) { cntL = 0; dcL = 0; }
    if (tid < 2 * NEV) nodL[tid] = (tid & 1) ? u[tid >> 1] : v[tid >> 1];
    __syncthreads();

    // ---- phase 1: scan adjacency row, compact into LDS, sum exp(S) ----
    float lsum = 0.f;
    for (int j = tid; j < N; j += 256) {
        if (A[base + j] > 0.f) {
            const float ev = expf(S[base + j]);
            lsum += ev;
            const int p = atomicAdd(&cntL, 1);
            if (p < MAXD) { nbrL_i[p] = j; nbrL_e[p] = ev; }
        }
    }
    rs[tid] = lsum;
    __syncthreads();
    for (int off = 128; off > 0; off >>= 1) {
        if (tid < off) rs[tid] += rs[tid + off];
        __syncthreads();
    }
    if (tid == 0) { sumL = rs[0]; deg[slot] = cntL; }
    __syncthreads();

    const int d = min(cntL, MAXD);
    const float rinv = 1.f / (sumL + 1e-7f);

    // ---- phase 1.5: per-neighbor latest-updater slot strictly before e ----
    for (int j0 = tid; j0 < d; j0 += 256) {
        const int j = nbrL_i[j0];
        int dep = -1;
        for (int s2 = 2 * e - 1; s2 >= 0; --s2)
            if (nodL[s2] == j) { dep = s2; break; }
        flagL[j0] = dep;                      // <0: static; >=0: dirty dep slot
    }
    __syncthreads();

    // ---- phase 2: Mstat over static neighbors ----
    {
        const int c = tid & 127, half = tid >> 7;
        float m = -INFINITY;
        for (int j0 = half; j0 < d; j0 += 2) {
            if (flagL[j0] < 0)
                m = fmaxf(m, nbrL_e[j0] * rinv * h_tab[(size_t)nbrL_i[j0] * H + c]);
        }
        redm[tid] = m;
        __syncthreads();
        if (tid < 128) Mstat[slot * H + c] = fmaxf(redm[c], redm[128 + c]);
    }

    // ---- phase 3: dirty list (latest-updater dep slots) ----
    for (int j0 = tid; j0 < d; j0 += 256) {
        const int dep = flagL[j0];
        if (dep >= 0) {
            const int p = atomicAdd(&dcL, 1);
            if (p < MAXDIRTY) { dlL_s[p] = dep; dlL_q[p] = nbrL_e[j0] * rinv; }
        }
    }
    __syncthreads();
    if (tid == 0) dcnt[slot] = dcL;
    const int nd = min(dcL, MAXDIRTY);
    for (int p = tid; p < nd; p += 256) {
        dl_s[slot * MAXDIRTY + p] = dlL_s[p];
        dl_q[slot * MAXDIRTY + p] = dlL_q[p];
    }
}

// ---------------------------------------------------------------------------
// k_parls: blocks 0..63 = par role (verbatim round 15, passed); block 64 =
// lam; blocks 65..84 = survival (verbatim r15 k_ls bodies, tid<64 guards).
// lam/surv read ONLY prior-dispatch data (d0/d1 from standalone k_emb) and
// never touch donebits — the proven protocol is undisturbed.
// ---------------------------------------------------------------------------
__global__ __launch_bounds__(256) void k_parls(
    const int* __restrict__ u, const int* __restrict__ v,
    const float* __restrict__ t, const int* __restrict__ kk,
    const int* __restrict__ u_o, const int* __restrict__ v_o,
    const float* __restrict__ lastt, const float* __restrict__ emb,
    const float* __restrict__ W_S, const float* __restrict__ W_R,
    const float* __restrict__ W_t, const float* __restrict__ W_h,
    const float* __restrict__ b_h,
    const float* __restrict__ psi, const float* __restrict__ b_om,
    const float* __restrict__ d0, const float* __restrict__ d1,
    const int* __restrict__ deg, const int* __restrict__ dcnt,
    const int* __restrict__ dl_s, const float* __restrict__ dl_q,
    const float* __restrict__ Mstat,
    float* __restrict__ z_slot, float* __restrict__ h_slot,
    unsigned long long* __restrict__ donebits,
    float* __restrict__ lamout, float* __restrict__ svout,
    float* __restrict__ z_out)
{
    const int bid = blockIdx.x;
    const int tid = threadIdx.x;

    if (bid >= NEV) {
        // ================= lam / survival roles (prior-dispatch reads only) ====
        if (bid == NEV) {
            if (tid < NEV) {
                const int b = tid;
                const int kv = kk[b];
                const float* dk = kv ? d1 : d0;
                const float g = 0.5f * (dk[u[b]] + dk[v[b]]) + b_om[kv];
                const float ps = psi[kv];
                const float x = fminf(75.f, fmaxf(-75.f, g / ps));
                lamout[b] = ps * log1pf(expf(x));
            }
        } else {
            const int s = bid - NEV - 1;
            if (tid < 64) {
                const int b = tid;
                const float p0 = psi[0], p1 = psi[1], bo0 = b_om[0], bo1 = b_om[1];
                const int vo = v_o[b * SS + s], uo = u_o[b * SS + s];
                float g, x;
                g = 0.5f * (d0[u[b]] + d0[vo]) + bo0; x = fminf(75.f, fmaxf(-75.f, g / p0));
                const float ru0 = p0 * log1pf(expf(x));
                g = 0.5f * (d1[u[b]] + d1[vo]) + bo1; x = fminf(75.f, fmaxf(-75.f, g / p1));
                const float ru1 = p1 * log1pf(expf(x));
                g = 0.5f * (d1[v[b]] + d1[uo]) + bo1; x = fminf(75.f, fmaxf(-75.f, g / p1));
                const float rv1 = p1 * log1pf(expf(x));
                float val = 2.f * (ru0 + ru1) + rv1;
#pragma unroll
                for (int off = 32; off > 0; off >>= 1) val += __shfl_xor(val, off);
                if (b == 0) svout[s] = val / (float)SS;
            }
        }
        return;
    }

    // ================= par role (verbatim round 15) ========================
    const int e = bid;
    const int r = tid >> 7;             // wave-uniform (waves 0-1: r=0, 2-3: r=1)
    const int c = tid & 127;
    const int slot = 2 * e + r;

    __shared__ __align__(16) float hs_s[2][128];
    __shared__ __align__(16) float zz_s[2][128];
    __shared__ __align__(16) float zn_s[2][128];
    __shared__ int   uL[NEV], vL[NEV];
    __shared__ int   zdepL[2], lastupL[2], nodeL[2];
    __shared__ float dtvL[2];
    __shared__ unsigned long long need_s;

    if (tid < NEV)                 uL[tid] = u[tid];
    else if (tid < 2 * NEV)        vL[tid - NEV] = v[tid - NEV];
    __syncthreads();

    // ---- per-slot metadata from the event list ----
    if (tid < 2) {
        const int sl = 2 * e + tid;
        const int node = tid ? uL[e] : vL[e];    // slot 2e -> v[e], 2e+1 -> u[e]
        nodeL[tid] = node;
        int zd = -1;
        for (int j = 2 * e - 1; j >= 0; --j) {
            const int nj = (j & 1) ? uL[j >> 1] : vL[j >> 1];
            if (nj == node) { zd = j; break; }
        }
        zdepL[tid] = zd;
        int lu = 1;
        for (int j = sl + 1; j < 2 * NEV; ++j) {
            const int nj = (j & 1) ? uL[j >> 1] : vL[j >> 1];
            if (nj == node) { lu = 0; break; }
        }
        lastupL[tid] = lu;
        const int dtn = tid ? vL[e] : uL[e];     // crossed: row v uses let[u], row u let[v]
        int pt = -1;
        for (int e2 = e - 1; e2 >= 0; --e2)
            if (uL[e2] == dtn || vL[e2] == dtn) { pt = e2; break; }
        const float lv = (pt >= 0) ? t[pt] : lastt[dtn];
        dtvL[tid] = t[e] - lv;
    }
    __syncthreads();

    // ---- build need-mask and spin (thread 0), then per-thread acquire ----
    if (tid == 0) {
        unsigned long long need = 0ull;
        for (int rr = 0; rr < 2; ++rr) {
            const int zd = zdepL[rr];
            if (zd >= 0) need |= 1ull << (zd >> 1);
            const int sl = 2 * e + rr;
            const int dn = min(dcnt[sl], MAXDIRTY);
            for (int p = 0; p < dn; ++p)
                need |= 1ull << (dl_s[sl * MAXDIRTY + p] >> 1);
        }
        need_s = need;
        if (need) {
            int guard = 0;
            while ((__hip_atomic_load(donebits, __ATOMIC_ACQUIRE,
                                      __HIP_MEMORY_SCOPE_AGENT) & need) != need) {
                __builtin_amdgcn_s_sleep(2);
                if (++guard > SPIN_GUARD) break;       // safety valve
            }
        }
    }
    __syncthreads();
    if (need_s) {   // per-thread acquire: invalidate stale cache lines on this CU
        unsigned long long db = __hip_atomic_load(donebits, __ATOMIC_ACQUIRE,
                                                  __HIP_MEMORY_SCOPE_AGENT);
        (void)db;
    }

    // ---- Phase A: hs (Mstat static max + dirty via h_slot) and z (versioned) ----
    {
        float m = Mstat[slot * H + c];
        const int dn = min(dcnt[slot], MAXDIRTY);
        for (int p = 0; p < dn; ++p) {
            const int ds = dl_s[slot * MAXDIRTY + p];
            const float q = dl_q[slot * MAXDIRTY + p];
            m = fmaxf(m, q * h_slot[ds * H + c]);
        }
        hs_s[r][c] = (deg[slot] > 0) ? 1.f / (1.f + __expf(-m)) : 0.f;
        const int zd = zdepL[r];
        zz_s[r][c] = (zd >= 0) ? z_slot[zd * H + c]
                               : emb[(size_t)nodeL[r] * H + c];
    }
    __syncthreads();

    // ---- Phase B: g = hs.W_S[c] + z.W_R[c] + dt*W_t[c]; sigmoid ----
    float g = 0.f;
    {
        const float4* ws4 = (const float4*)(W_S + (size_t)c * H);
        const float4* wr4 = (const float4*)(W_R + (size_t)c * H);
#pragma unroll
        for (int i = 0; i < 32; ++i) {
            const float4 a = ws4[i];
            const float4 b = wr4[i];
            const float4 hh = *(const float4*)&hs_s[r][4 * i];   // LDS broadcast
            const float4 zz = *(const float4*)&zz_s[r][4 * i];
            g += hh.x * a.x + hh.y * a.y + hh.z * a.z + hh.w * a.w +
                 zz.x * b.x + zz.y * b.y + zz.z * b.z + zz.w * b.w;
        }
    }
    g += dtvL[r] * W_t[c];
    const float zv = 1.f / (1.f + __expf(-g));
    zn_s[r][c] = zv;
    z_slot[slot * H + c] = zv;                      // versioned publish (z)
    if (lastupL[r])                                 // final updater writes output
        z_out[(size_t)nodeL[r] * H + c] = zv;
    __syncthreads();                                // zn_s ready for phase C

    // ---- Phase C: publish h_slot[slot] (unconditional) ----
    {
        float h = 0.f;
        const float4* wh4 = (const float4*)(W_h + (size_t)c * H);
#pragma unroll
        for (int i = 0; i < 32; ++i) {
            const float4 a = wh4[i];
            const float4 zz = *(const float4*)&zn_s[r][4 * i];
            h += zz.x * a.x + zz.y * a.y + zz.z * a.z + zz.w * a.w;
        }
        h_slot[slot * H + c] = h + b_h[c];
    }

    // ---- release (unconditional) ----
    __syncthreads();
    if (tid == 0) {
        __threadfence();                            // agent-scope write visibility
        __hip_atomic_fetch_or(donebits, 1ull << e, __ATOMIC_RELEASE,
                              __HIP_MEMORY_SCOPE_AGENT);
    }
}

// ---------------------------------------------------------------------------
extern "C" void kernel_launch(void* const* d_in, const int* in_sizes, int n_in,
                              void* d_out, int out_size, void* d_ws, size_t ws_size,
                              hipStream_t stream)
{
    const int*   u        = (const int*)d_in[0];
    const int*   v        = (const int*)d_in[1];
    const float* t        = (const float*)d_in[2];
    const int*   k        = (const int*)d_in[3];
    const int*   u_others = (const int*)d_in[4];
    const int*   v_others = (const int*)d_in[5];
    const float* A        = (const float*)d_in[6];
    const float* S        = (const float*)d_in[7];
    const float* emb      = (const float*)d_in[8];
    const float* lastt    = (const float*)d_in[9];
    const float* W_S      = (const float*)d_in[10];
    const float* W_R      = (const float*)d_in[11];
    const float* W_t      = (const float*)d_in[12];
    const float* W_h      = (const float*)d_in[13];
    const float* b_h      = (const float*)d_in[14];
    const float* psi      = (const float*)d_in[15];
    const float* W_om     = (const float*)d_in[16];
    const float* b_om     = (const float*)d_in[17];
    (void)in_sizes; (void)n_in; (void)out_size; (void)ws_size;

    float* wsf    = (float*)d_ws;
    float* h_tab  = wsf;                            // N*H
    float* d0     = h_tab + (size_t)N * H;          // N
    float* d1     = d0 + N;                         // N
    float* Mstat  = d1 + N;                         // 128*H
    float* dl_q   = Mstat + 128 * H;                // 128*MAXDIRTY
    float* z_slot = dl_q + 128 * MAXDIRTY;          // 128*H
    float* h_slot = z_slot + 128 * H;               // 128*H
    int*   deg    = (int*)(h_slot + 128 * H);       // 128
    int*   dcnt   = deg + 128;                      // 128
    int*   dl_s   = dcnt + 128;                     // 128*MAXDIRTY
    unsigned long long* donebits = (unsigned long long*)(dl_s + 128 * MAXDIRTY);

    float* out    = (float*)d_out;
    float* lamout = out;            // [64]
    float* svout  = out + NEV;      // [20]
    float* z_out  = out + NEV + SS; // [N*H]

    k_emb<<<N / RPB, 512, 0, stream>>>(emb, W_h, b_h, W_om, h_tab, z_out, d0, d1);
    k_nbrdm<<<128, 256, 0, stream>>>(u, v, A, S, h_tab,
                                     deg, Mstat, dcnt, dl_s, dl_q, donebits);
    k_parls<<<NEV + 1 + SS, 256, 0, stream>>>(u, v, t, k, u_others, v_others,
                                              lastt, emb, W_S, W_R, W_t, W_h, b_h,
                                              psi, b_om, d0, d1,
                                              deg, dcnt, dl_s, dl_q, Mstat,
                                              z_slot, h_slot, donebits,
                                              lamout, svout, z_out);
}